// Round 11
// baseline (1671.603 us; speedup 1.0000x reference)
//
#include <hip/hip_runtime.h>
#include <math.h>

#define ROI 400
#define HEADS 4
#define DH 100
#define NB 64
#define HIDF 800
#define NC 2
#define KPOOL 280
#define ATT_SCALE 0.1f
#define CTT 10

typedef __attribute__((ext_vector_type(8))) short short8v;
typedef __attribute__((ext_vector_type(8))) unsigned short u16x8;
typedef __attribute__((ext_vector_type(4))) float f32x4;

union U8 { short8v v; unsigned short u[8]; };

__device__ __forceinline__ unsigned short f2bf(float x) {
  unsigned int u = __float_as_uint(x);
  u += 0x7fffu + ((u >> 16) & 1u);
  return (unsigned short)(u >> 16);
}
__device__ __forceinline__ void split2(float x, unsigned short& h, unsigned short& l) {
  h = f2bf(x);
  float hf = __uint_as_float(((unsigned int)h) << 16);
  l = f2bf(x - hf);
}

// ---------------------------------------------------------------- preprocess (two-stage)
__global__ __launch_bounds__(256) void pre_partial_kernel(const float* __restrict__ in,
                                                          double* __restrict__ pp) {
  int b = blockIdx.x, t = blockIdx.y;
  const float* p = in + (size_t)b * ROI * (2 * ROI);
  float s = 0.f, ss = 0.f;
  for (int e = threadIdx.x; e < 40 * ROI; e += 256) {
    int r = 40 * t + e / ROI, c = e % ROI;
    float v = log10f(p[(size_t)r * (2 * ROI) + ROI + c] + 1.0f);
    s += v; ss += v * v;
  }
  __shared__ double rs[256], rss[256];
  rs[threadIdx.x] = s; rss[threadIdx.x] = ss;
  __syncthreads();
  for (int st = 128; st > 0; st >>= 1) {
    if (threadIdx.x < st) { rs[threadIdx.x] += rs[threadIdx.x + st]; rss[threadIdx.x] += rss[threadIdx.x + st]; }
    __syncthreads();
  }
  if (threadIdx.x == 0) {
    pp[(b * CTT + t) * 2 + 0] = rs[0];
    pp[(b * CTT + t) * 2 + 1] = rss[0];
  }
}

__global__ __launch_bounds__(64) void pre_final_kernel(const double* __restrict__ pp,
                                                       float* __restrict__ meanb,
                                                       float* __restrict__ stdb) {
  int b = threadIdx.x;
  double s = 0.0, ss = 0.0;
  for (int t = 0; t < CTT; ++t) { s += pp[(b * CTT + t) * 2]; ss += pp[(b * CTT + t) * 2 + 1]; }
  const int n = ROI * ROI;
  double mean = s / n;
  double var = (ss - s * s / n) / (double)(n - 1);
  meanb[b] = (float)mean;
  stdb[b]  = (float)(sqrt(var) + 1e-6);
}

__global__ __launch_bounds__(256) void build_m_kernel(const float* __restrict__ in,
                                                      const float* __restrict__ sel,
                                                      const float* __restrict__ meanb,
                                                      const float* __restrict__ stdb,
                                                      float* __restrict__ M) {
  size_t e = (size_t)blockIdx.x * blockDim.x + threadIdx.x;
  const size_t total = (size_t)NB * ROI * ROI;
  if (e >= total) return;
  int c = (int)(e % ROI);
  int r = (int)((e / ROI) % ROI);
  int b = (int)(e / ((size_t)ROI * ROI));
  const float* row = in + ((size_t)b * ROI + r) * (2 * ROI);
  float v = log10f(row[ROI + c] + 1.0f);
  float sg = 1.0f / (1.0f + expf(-sel[r * ROI + c]));
  M[e] = ((v - meanb[b]) / stdb[b]) * sg;
}

// ---------------------------------------------------------------- batched weight pack (one launch / depth)
struct PackDesc {
  const float* W;
  unsigned short* WH;
  unsigned short* WL;
  int K, N, nbx, blk0;
};
struct PackAll { PackDesc d[6]; };

__global__ __launch_bounds__(256) void packall_kernel(PackAll pa) {
  int gb = blockIdx.x;
  int i = 0;
#pragma unroll
  for (int j = 1; j < 6; ++j) if (gb >= pa.d[j].blk0) i = j;
  const float* __restrict__ W = pa.d[i].W;
  unsigned short* __restrict__ WH = pa.d[i].WH;
  unsigned short* __restrict__ WL = pa.d[i].WL;
  const int K = pa.d[i].K, N = pa.d[i].N;
  int lb = gb - pa.d[i].blk0;
  int bn = (lb % pa.d[i].nbx) * 64;
  int bk = (lb / pa.d[i].nbx) * 64;

  __shared__ float t[64][68];
  int r = threadIdx.x >> 2;
  int c0 = (threadIdx.x & 3) << 4;
  int gk = bk + r;
#pragma unroll
  for (int q = 0; q < 4; ++q) {
    int c = c0 + 4 * q;
    float4 v = make_float4(0.f, 0.f, 0.f, 0.f);
    if (gk < K && bn + c < N) v = *(const float4*)(W + (size_t)gk * N + bn + c);
    *(float4*)&t[r][c] = v;
  }
  __syncthreads();
  int gn = bn + r;
#pragma unroll
  for (int q = 0; q < 4; ++q) {
    int c = c0 + 4 * q;
    int gkk = bk + c;
    if (gn < N && gkk < K) {
      ushort4 h, l;
      split2(t[c + 0][r], h.x, l.x);
      split2(t[c + 1][r], h.y, l.y);
      split2(t[c + 2][r], h.z, l.z);
      split2(t[c + 3][r], h.w, l.w);
      *(ushort4*)(WH + (size_t)gn * K + gkk) = h;
      *(ushort4*)(WL + (size_t)gn * K + gkk) = l;
    }
  }
}

// ---------------------------------------------------------------- activation pack
__global__ __launch_bounds__(256) void packa_kernel(const float* __restrict__ A, int lda, int K, int total4,
                                                    unsigned short* __restrict__ AH,
                                                    unsigned short* __restrict__ AL) {
  int e = blockIdx.x * 256 + threadIdx.x;
  if (e >= total4) return;
  int idx = e << 2;
  int row = idx / K, k = idx - row * K;
  float4 v = *(const float4*)(A + (size_t)row * lda + k);
  ushort4 h, l;
  split2(v.x, h.x, l.x); split2(v.y, h.y, l.y);
  split2(v.z, h.z, l.z); split2(v.w, h.w, l.w);
  *(ushort4*)(AH + (size_t)row * K + k) = h;
  *(ushort4*)(AL + (size_t)row * K + k) = l;
}

// ---------------------------------------------------------------- MFMA split-bf16 GEMM
// EPI: 0 plain float, 2 bias+res float, 4 bias+gelu -> split out, 5 bias+res -> float+split, 6 plain -> split out
#define TBM 128
#define TBN 128
#define TBK 32
#define KP 40

template<int EPI>
__global__ __launch_bounds__(256) void mgemm_kernel(const unsigned short* __restrict__ AHp,
                                                    const unsigned short* __restrict__ ALp,
                                                    const unsigned short* __restrict__ WH,
                                                    const unsigned short* __restrict__ WL,
                                                    const float* __restrict__ bias,
                                                    const float* __restrict__ res, int ldr,
                                                    float* __restrict__ C,
                                                    unsigned short* __restrict__ CH,
                                                    unsigned short* __restrict__ CL,
                                                    int M, int N, int K) {
  __shared__ unsigned short Ah[TBM][KP], Al[TBM][KP], Bh[TBN][KP], Bl[TBN][KP];
  const int tid = threadIdx.x;
  const int lane = tid & 63;
  const int wid = tid >> 6;
  const int wm = wid >> 1, wn = wid & 1;
  const int l15 = lane & 15, l4 = lane >> 4;
  const int bm = blockIdx.y * TBM;
  const int bn = blockIdx.x * TBN;

  f32x4 acc[4][4];
#pragma unroll
  for (int i = 0; i < 4; ++i)
#pragma unroll
    for (int j = 0; j < 4; ++j) acc[i][j] = (f32x4){0.f, 0.f, 0.f, 0.f};

  for (int k0 = 0; k0 < K; k0 += TBK) {
#pragma unroll
    for (int it = 0; it < 2; ++it) {
      int c = tid + 256 * it;
      int row = c >> 2;
      int kq = (c & 3) << 3;
      u16x8 vh = {0, 0, 0, 0, 0, 0, 0, 0};
      u16x8 vl = {0, 0, 0, 0, 0, 0, 0, 0};
      if (k0 + kq + 8 <= K) {
        size_t off = (size_t)(bm + row) * K + k0 + kq;
        vh = *(const u16x8*)(AHp + off);
        vl = *(const u16x8*)(ALp + off);
      }
      *(u16x8*)&Ah[row][kq] = vh;
      *(u16x8*)&Al[row][kq] = vl;
    }
#pragma unroll
    for (int it = 0; it < 2; ++it) {
      int c = tid + 256 * it;
      int row = c >> 2;
      int kq = (c & 3) << 3;
      int gn = bn + row;
      u16x8 vh = {0, 0, 0, 0, 0, 0, 0, 0};
      u16x8 vl = {0, 0, 0, 0, 0, 0, 0, 0};
      if (gn < N && k0 + kq + 8 <= K) {
        size_t off = (size_t)gn * K + k0 + kq;
        vh = *(const u16x8*)(WH + off);
        vl = *(const u16x8*)(WL + off);
      }
      *(u16x8*)&Bh[row][kq] = vh;
      *(u16x8*)&Bl[row][kq] = vl;
    }
    __syncthreads();

    short8v ah[4], alo[4], bh[4], blo[4];
#pragma unroll
    for (int mf = 0; mf < 4; ++mf) {
      int r = wm * 64 + mf * 16 + l15;
      ah[mf]  = *(const short8v*)&Ah[r][l4 * 8];
      alo[mf] = *(const short8v*)&Al[r][l4 * 8];
    }
#pragma unroll
    for (int nf = 0; nf < 4; ++nf) {
      int r = wn * 64 + nf * 16 + l15;
      bh[nf]  = *(const short8v*)&Bh[r][l4 * 8];
      blo[nf] = *(const short8v*)&Bl[r][l4 * 8];
    }
#pragma unroll
    for (int mf = 0; mf < 4; ++mf)
#pragma unroll
      for (int nf = 0; nf < 4; ++nf) {
        acc[mf][nf] = __builtin_amdgcn_mfma_f32_16x16x32_bf16(ah[mf], bh[nf], acc[mf][nf], 0, 0, 0);
        acc[mf][nf] = __builtin_amdgcn_mfma_f32_16x16x32_bf16(ah[mf], blo[nf], acc[mf][nf], 0, 0, 0);
        acc[mf][nf] = __builtin_amdgcn_mfma_f32_16x16x32_bf16(alo[mf], bh[nf], acc[mf][nf], 0, 0, 0);
      }
    __syncthreads();
  }

#pragma unroll
  for (int mf = 0; mf < 4; ++mf) {
#pragma unroll
    for (int nf = 0; nf < 4; ++nf) {
      int col = bn + wn * 64 + nf * 16 + l15;
      if (col < N) {
        float bv = (EPI >= 1 && EPI != 6) ? bias[col] : 0.f;
        int row0 = bm + wm * 64 + mf * 16 + l4 * 4;
#pragma unroll
        for (int r = 0; r < 4; ++r) {
          float v = acc[mf][nf][r] + bv;
          int row = row0 + r;
          if (EPI == 2 || EPI == 5) v += res[(size_t)row * ldr + col];
          if (EPI == 4) {
            v = 0.5f * v * (1.0f + erff(v * 0.70710678118654752f));
            unsigned short hh, ll;
            split2(v, hh, ll);
            CH[(size_t)row * N + col] = hh;
            CL[(size_t)row * N + col] = ll;
          } else if (EPI == 5) {
            C[(size_t)row * N + col] = v;
            unsigned short hh, ll;
            split2(v, hh, ll);
            CH[(size_t)row * N + col] = hh;
            CL[(size_t)row * N + col] = ll;
          } else if (EPI == 6) {
            unsigned short hh, ll;
            split2(v, hh, ll);
            CH[(size_t)row * N + col] = hh;
            CL[(size_t)row * N + col] = ll;
          } else {
            C[(size_t)row * N + col] = v;
          }
        }
      }
    }
  }
}

// ---------------------------------------------------------------- MFMA flash attention (128 q rows, 8 waves)
#define FBJ 32
#define FBI 128

__global__ __launch_bounds__(512) void fattn_kernel(const unsigned short* __restrict__ QKVH,
                                                    const unsigned short* __restrict__ QKVL,
                                                    const float* __restrict__ Mm,
                                                    unsigned short* __restrict__ OH,
                                                    unsigned short* __restrict__ OL, int N) {
  const int ldq = 3 * ROI;
  __shared__ unsigned short Kh[FBJ][136], Kl[FBJ][136];
  __shared__ unsigned short Vth[112][40], Vtl[112][40];
  __shared__ unsigned short Ph[FBI][40], Pl[FBI][40];

  const int tid = threadIdx.x;
  const int lane = tid & 63;
  const int w = tid >> 6;              // 0..7 -> q rows 16w..16w+15
  const int l15 = lane & 15, l4 = lane >> 4;
  const int i0 = blockIdx.x * FBI;
  const int h = blockIdx.y, b = blockIdx.z;

  const float* Mb = Mm + (size_t)b * N * N;

  for (int e = tid; e < 12 * 40; e += 512) {
    Vth[100 + e / 40][e % 40] = 0; Vtl[100 + e / 40][e % 40] = 0;
  }

  // Q fragments straight from split planes
  int qr = i0 + 16 * w + l15; if (qr >= N) qr = N - 1;
  const unsigned short* qrH = QKVH + ((size_t)b * N + qr) * ldq + h * DH;
  const unsigned short* qrL = QKVL + ((size_t)b * N + qr) * ldq + h * DH;
  short8v qh[4], ql[4];
#pragma unroll
  for (int kg = 0; kg < 4; ++kg) {
    int d0v = kg * 32 + l4 * 8;
    U8 th, tl;
    if (d0v + 8 <= DH) {
      *(ushort4*)&th.u[0] = *(const ushort4*)(qrH + d0v);
      *(ushort4*)&th.u[4] = *(const ushort4*)(qrH + d0v + 4);
      *(ushort4*)&tl.u[0] = *(const ushort4*)(qrL + d0v);
      *(ushort4*)&tl.u[4] = *(const ushort4*)(qrL + d0v + 4);
    } else if (d0v < DH) {
      *(ushort4*)&th.u[0] = *(const ushort4*)(qrH + d0v);
      *(ushort4*)&tl.u[0] = *(const ushort4*)(qrL + d0v);
#pragma unroll
      for (int j = 4; j < 8; ++j) { th.u[j] = 0; tl.u[j] = 0; }
    } else {
#pragma unroll
      for (int j = 0; j < 8; ++j) { th.u[j] = 0; tl.u[j] = 0; }
    }
    qh[kg] = th.v; ql[kg] = tl.v;
  }

  float m_i[4], l_i[4];
  f32x4 o[7];
#pragma unroll
  for (int r = 0; r < 4; ++r) { m_i[r] = -INFINITY; l_i[r] = 0.f; }
#pragma unroll
  for (int ff = 0; ff < 7; ++ff) o[ff] = (f32x4){0.f, 0.f, 0.f, 0.f};

  const int njt = (N + FBJ - 1) / FBJ;
  for (int jt = 0; jt < njt; ++jt) {
    const int j0 = jt * FBJ;
    const int kv0 = j0 + l15, kv1 = j0 + l15 + 16;

    // prefetch M tile into registers (hidden under staging + QK^T)
    float mpre[4][2];
#pragma unroll
    for (int r = 0; r < 4; ++r) {
      int gq = i0 + 16 * w + l4 * 4 + r;
      int gqc = (gq < N) ? gq : N - 1;
      const float* Mr = Mb + (size_t)gqc * N;
      mpre[r][0] = (kv0 < N) ? Mr[kv0] : 0.f;
      mpre[r][1] = (kv1 < N) ? Mr[kv1] : 0.f;
    }

    __syncthreads();
    // stage K: pure ushort4 copies from planes
    for (int e = tid; e < 32 * 32; e += 512) {
      int kv = e >> 5;
      int dq = (e & 31) << 2;
      int gj = j0 + kv; if (gj >= N) gj = N - 1;
      size_t off = ((size_t)b * N + gj) * ldq + ROI + h * DH + dq;
      ushort4 hh = {0, 0, 0, 0}, ll = {0, 0, 0, 0};
      if (dq < DH) { hh = *(const ushort4*)(QKVH + off); ll = *(const ushort4*)(QKVL + off); }
      *(ushort4*)&Kh[kv][dq] = hh;
      *(ushort4*)&Kl[kv][dq] = ll;
    }
    // stage V transposed: ushort4 loads + OR/shift packs, conflict-free u32 stores
    for (int e = tid; e < 400; e += 512) {
      int kvp = e & 15;
      int dq = (e >> 4) << 2;
      int gj0 = j0 + 2 * kvp;     if (gj0 >= N) gj0 = N - 1;
      int gj1 = j0 + 2 * kvp + 1; if (gj1 >= N) gj1 = N - 1;
      size_t o0 = ((size_t)b * N + gj0) * ldq + 2 * ROI + h * DH + dq;
      size_t o1 = ((size_t)b * N + gj1) * ldq + 2 * ROI + h * DH + dq;
      ushort4 aH = *(const ushort4*)(QKVH + o0);
      ushort4 bH = *(const ushort4*)(QKVH + o1);
      ushort4 aL = *(const ushort4*)(QKVL + o0);
      ushort4 bL = *(const ushort4*)(QKVL + o1);
      *(unsigned int*)&Vth[dq + 0][2 * kvp] = (unsigned int)aH.x | ((unsigned int)bH.x << 16);
      *(unsigned int*)&Vth[dq + 1][2 * kvp] = (unsigned int)aH.y | ((unsigned int)bH.y << 16);
      *(unsigned int*)&Vth[dq + 2][2 * kvp] = (unsigned int)aH.z | ((unsigned int)bH.z << 16);
      *(unsigned int*)&Vth[dq + 3][2 * kvp] = (unsigned int)aH.w | ((unsigned int)bH.w << 16);
      *(unsigned int*)&Vtl[dq + 0][2 * kvp] = (unsigned int)aL.x | ((unsigned int)bL.x << 16);
      *(unsigned int*)&Vtl[dq + 1][2 * kvp] = (unsigned int)aL.y | ((unsigned int)bL.y << 16);
      *(unsigned int*)&Vtl[dq + 2][2 * kvp] = (unsigned int)aL.z | ((unsigned int)bL.z << 16);
      *(unsigned int*)&Vtl[dq + 3][2 * kvp] = (unsigned int)aL.w | ((unsigned int)bL.w << 16);
    }
    __syncthreads();

    f32x4 sacc[2];
    sacc[0] = (f32x4){0.f, 0.f, 0.f, 0.f};
    sacc[1] = (f32x4){0.f, 0.f, 0.f, 0.f};
#pragma unroll
    for (int kg = 0; kg < 4; ++kg) {
#pragma unroll
      for (int f = 0; f < 2; ++f) {
        short8v bh = *(const short8v*)&Kh[l15 + 16 * f][kg * 32 + l4 * 8];
        short8v bl = *(const short8v*)&Kl[l15 + 16 * f][kg * 32 + l4 * 8];
        sacc[f] = __builtin_amdgcn_mfma_f32_16x16x32_bf16(qh[kg], bh, sacc[f], 0, 0, 0);
        sacc[f] = __builtin_amdgcn_mfma_f32_16x16x32_bf16(qh[kg], bl, sacc[f], 0, 0, 0);
        sacc[f] = __builtin_amdgcn_mfma_f32_16x16x32_bf16(ql[kg], bh, sacc[f], 0, 0, 0);
      }
    }

#pragma unroll
    for (int r = 0; r < 4; ++r) {
      float s0 = (kv0 < N) ? sacc[0][r] * ATT_SCALE * (1.0f + mpre[r][0]) : -INFINITY;
      float s1 = (kv1 < N) ? sacc[1][r] * ATT_SCALE * (1.0f + mpre[r][1]) : -INFINITY;
      float rm = fmaxf(s0, s1);
      rm = fmaxf(rm, __shfl_xor(rm, 1, 16));
      rm = fmaxf(rm, __shfl_xor(rm, 2, 16));
      rm = fmaxf(rm, __shfl_xor(rm, 4, 16));
      rm = fmaxf(rm, __shfl_xor(rm, 8, 16));
      float nm = fmaxf(m_i[r], rm);
      float fr = expf(m_i[r] - nm);
      float p0 = (kv0 < N) ? expf(s0 - nm) : 0.f;
      float p1 = (kv1 < N) ? expf(s1 - nm) : 0.f;
      float ts = p0 + p1;
      ts += __shfl_xor(ts, 1, 16);
      ts += __shfl_xor(ts, 2, 16);
      ts += __shfl_xor(ts, 4, 16);
      ts += __shfl_xor(ts, 8, 16);
      l_i[r] = l_i[r] * fr + ts;
      m_i[r] = nm;
#pragma unroll
      for (int ff = 0; ff < 7; ++ff) o[ff][r] *= fr;
      unsigned short h0, l0, h1, l1;
      split2(p0, h0, l0); split2(p1, h1, l1);
      int prow = 16 * w + l4 * 4 + r;
      Ph[prow][l15] = h0;      Pl[prow][l15] = l0;
      Ph[prow][l15 + 16] = h1; Pl[prow][l15 + 16] = l1;
    }
    __syncthreads();

    short8v ph = *(const short8v*)&Ph[16 * w + l15][l4 * 8];
    short8v pl = *(const short8v*)&Pl[16 * w + l15][l4 * 8];
#pragma unroll
    for (int ff = 0; ff < 7; ++ff) {
      short8v vh = *(const short8v*)&Vth[ff * 16 + l15][l4 * 8];
      short8v vl = *(const short8v*)&Vtl[ff * 16 + l15][l4 * 8];
      o[ff] = __builtin_amdgcn_mfma_f32_16x16x32_bf16(ph, vh, o[ff], 0, 0, 0);
      o[ff] = __builtin_amdgcn_mfma_f32_16x16x32_bf16(ph, vl, o[ff], 0, 0, 0);
      o[ff] = __builtin_amdgcn_mfma_f32_16x16x32_bf16(pl, vh, o[ff], 0, 0, 0);
    }
  }

#pragma unroll
  for (int r = 0; r < 4; ++r) {
    int gq = i0 + 16 * w + l4 * 4 + r;
    if (gq < N) {
      float inv = 1.0f / l_i[r];
      size_t rowoff = ((size_t)b * N + gq) * ROI + h * DH;
#pragma unroll
      for (int ff = 0; ff < 7; ++ff) {
        int d = ff * 16 + l15;
        if (d < DH) {
          unsigned short hh, ll;
          split2(o[ff][r] * inv, hh, ll);
          OH[rowoff + d] = hh;
          OL[rowoff + d] = ll;
        }
      }
    }
  }
}

// ---------------------------------------------------------------- layernorm
__global__ __launch_bounds__(128) void ln_kernel(const float* __restrict__ Y, const float* __restrict__ g,
                                                 const float* __restrict__ bta, float* __restrict__ X) {
  int row = blockIdx.x;
  const float* y = Y + (size_t)row * ROI;
  float* x = X + (size_t)row * ROI;
  int tid = threadIdx.x;
  __shared__ float red[128];
  float s = 0.f;
  for (int c = tid; c < ROI; c += 128) s += y[c];
  red[tid] = s; __syncthreads();
  for (int st = 64; st > 0; st >>= 1) { if (tid < st) red[tid] += red[tid + st]; __syncthreads(); }
  float mu = red[0] / ROI;
  __syncthreads();
  float v = 0.f;
  for (int c = tid; c < ROI; c += 128) { float d = y[c] - mu; v += d * d; }
  red[tid] = v; __syncthreads();
  for (int st = 64; st > 0; st >>= 1) { if (tid < st) red[tid] += red[tid + st]; __syncthreads(); }
  float rstd = rsqrtf(red[0] / ROI + 1e-5f);
  for (int c = tid; c < ROI; c += 128) x[c] = (y[c] - mu) * rstd * g[c] + bta[c];
}

// ---------------------------------------------------------------- column-mean partials
__global__ __launch_bounds__(128) void colmean_kernel(const float* __restrict__ X,
                                                      float* __restrict__ gfp, int N) {
  int b = blockIdx.x, t = blockIdx.y, tid = threadIdx.x;
  int per = (N + CTT - 1) / CTT;
  int n0 = t * per, n1 = n0 + per;
  if (n1 > N) n1 = N;
  float a0 = 0.f, a1 = 0.f, a2 = 0.f, a3 = 0.f;
  for (int n = n0; n < n1; ++n) {
    const float* row = X + ((size_t)b * N + n) * ROI;
    a0 += row[tid]; a1 += row[tid + 128]; a2 += row[tid + 256];
    if (tid < 16) a3 += row[tid + 384];
  }
  float* g = gfp + ((size_t)b * CTT + t) * ROI;
  g[tid] = a0; g[tid + 128] = a1; g[tid + 256] = a2;
  if (tid < 16) g[tid + 384] = a3;
}

// ---------------------------------------------------------------- classifier head (from partials)
__global__ __launch_bounds__(128) void head_kernel(const float* __restrict__ gfp,
                                                   const float* __restrict__ r1w, const float* __restrict__ r1b,
                                                   const float* __restrict__ r2w, const float* __restrict__ r2b,
                                                   float* __restrict__ probs, int N) {
  int b = blockIdx.x, tid = threadIdx.x;
  __shared__ float gf[ROI];
  __shared__ float hid[128];
  for (int c = tid; c < ROI; c += 128) {
    float s = 0.f;
    for (int t = 0; t < CTT; ++t) s += gfp[((size_t)b * CTT + t) * ROI + c];
    gf[c] = s / (float)N;
  }
  __syncthreads();
  {
    float a = r1b[tid];
    for (int k = 0; k < ROI; ++k) a += gf[k] * r1w[k * 128 + tid];
    hid[tid] = (a >= 0.f) ? a : 0.01f * a;
  }
  __syncthreads();
  if (tid < NC) {
    float l = r2b[tid];
    for (int k = 0; k < 128; ++k) l += hid[k] * r2w[k * NC + tid];
    gf[tid] = l;
  }
  __syncthreads();
  if (tid == 0) {
    float m = fmaxf(gf[0], gf[1]);
    float e0 = expf(gf[0] - m), e1 = expf(gf[1] - m);
    float inv = 1.f / (e0 + e1);
    probs[b * NC + 0] = e0 * inv;
    probs[b * NC + 1] = e1 * inv;
  }
}

// ---------------------------------------------------------------- final output (from partials)
__global__ __launch_bounds__(128) void finalize_kernel(const float* __restrict__ gfp,
                                                       const float* __restrict__ probs,
                                                       float* __restrict__ out, int N) {
  int b = blockIdx.x, tid = threadIdx.x;
  __shared__ float f[ROI];
  __shared__ float red[128];
  for (int c = tid; c < ROI; c += 128) {
    float s = 0.f;
    for (int t = 0; t < CTT; ++t) s += gfp[((size_t)b * CTT + t) * ROI + c];
    f[c] = s / (float)N;
  }
  __syncthreads();
  float ls = 0.f;
  for (int c = tid; c < ROI; c += 128) ls += f[c] * f[c];
  red[tid] = ls; __syncthreads();
  for (int st = 64; st > 0; st >>= 1) { if (tid < st) red[tid] += red[tid + st]; __syncthreads(); }
  float inv = 1.f / fmaxf(sqrtf(red[0]), 1e-12f);
  for (int c = tid; c < ROI; c += 128) out[b * ROI + c] = f[c] * inv;
  if (tid < NC) out[NB * ROI + b * NC + tid] = 0.5f * (probs[b * NC + tid] + probs[NB * NC + b * NC + tid]);
}

// ---------------------------------------------------------------- pooling
__global__ __launch_bounds__(128) void score_kernel(const float* __restrict__ M, const float* __restrict__ X,
                                                    const float* __restrict__ pws, const float* __restrict__ pwf,
                                                    const float* __restrict__ pmw, const float* __restrict__ pmb,
                                                    float* __restrict__ scores) {
  int i = blockIdx.x, b = blockIdx.y, tid = threadIdx.x;
  const float* mr = M + ((size_t)b * ROI + i) * ROI;
  const float* xr = X + ((size_t)b * ROI + i) * ROI;
  float s1 = 0.f, s2 = 0.f;
  for (int j = tid; j < ROI; j += 128) { s1 += mr[j] * pws[j]; s2 += xr[j] * pwf[j]; }
  __shared__ float r1[128], r2[128];
  r1[tid] = s1; r2[tid] = s2; __syncthreads();
  for (int st = 64; st > 0; st >>= 1) {
    if (tid < st) { r1[tid] += r1[tid + st]; r2[tid] += r2[tid + st]; }
    __syncthreads();
  }
  if (tid == 0) {
    float a = fabsf(r1[0]), c = fabsf(r2[0]);
    float z = a * pmw[0] + c * pmw[1] + pmb[0];
    scores[b * ROI + i] = 1.f / (1.f + expf(-z));
  }
}

__global__ __launch_bounds__(128) void select_kernel(const float* __restrict__ scores, int* __restrict__ idx) {
  int b = blockIdx.x, tid = threadIdx.x;
  __shared__ float sc[ROI];
  __shared__ int sel[ROI];
  for (int i = tid; i < ROI; i += 128) sc[i] = scores[b * ROI + i];
  __syncthreads();
  for (int i = tid; i < ROI; i += 128) {
    float si = sc[i];
    int rank = 0;
    for (int j = 0; j < ROI; ++j) {
      float sj = sc[j];
      rank += (sj > si) || (sj == si && j < i);
    }
    sel[i] = (rank < KPOOL) ? 1 : 0;
  }
  __syncthreads();
  for (int i = tid; i < ROI; i += 128) {
    if (sel[i]) {
      int pos = 0;
      for (int j = 0; j < i; ++j) pos += sel[j];
      idx[b * KPOOL + pos] = i;
    }
  }
}

__global__ __launch_bounds__(128) void gatherx_kernel(const float* __restrict__ X, const float* __restrict__ scores,
                                                      const int* __restrict__ idx, float* __restrict__ Xp,
                                                      unsigned short* __restrict__ XpH,
                                                      unsigned short* __restrict__ XpL) {
  int p = blockIdx.x % KPOOL, b = blockIdx.x / KPOOL, tid = threadIdx.x;
  int src = idx[b * KPOOL + p];
  float sw = scores[b * ROI + src];
  const float* xr = X + ((size_t)b * ROI + src) * ROI;
  size_t ro = ((size_t)b * KPOOL + p) * ROI;
  float* o = Xp + ro;
  for (int c = tid; c < ROI; c += 128) {
    float v = xr[c] * sw;
    o[c] = v;
    unsigned short hh, ll;
    split2(v, hh, ll);
    XpH[ro + c] = hh;
    XpL[ro + c] = ll;
  }
}

__global__ __launch_bounds__(128) void gatherm_kernel(const float* __restrict__ M, const int* __restrict__ idx,
                                                      float* __restrict__ Mp) {
  int p = blockIdx.x % KPOOL, b = blockIdx.x / KPOOL, tid = threadIdx.x;
  __shared__ int id[KPOOL];
  for (int q = tid; q < KPOOL; q += 128) id[q] = idx[b * KPOOL + q];
  __syncthreads();
  int src = idx[b * KPOOL + p];
  const float* mr = M + ((size_t)b * ROI + src) * ROI;
  float* o = Mp + ((size_t)b * KPOOL + p) * KPOOL;
  for (int q = tid; q < KPOOL; q += 128) o[q] = mr[id[q]];
}

// ---------------------------------------------------------------- host orchestration
template<int EPI>
static inline void mgemm(const unsigned short* AH, const unsigned short* AL,
                         const unsigned short* WH, const unsigned short* WL,
                         const float* bias, const float* res, int ldr,
                         float* C, unsigned short* CH, unsigned short* CL,
                         int M, int N, int K, hipStream_t st) {
  dim3 g((N + TBN - 1) / TBN, M / TBM);
  mgemm_kernel<EPI><<<g, 256, 0, st>>>(AH, AL, WH, WL, bias, res, ldr, C, CH, CL, M, N, K);
}

static inline void packa(const float* A, int lda, int M, int K, unsigned short* AH, unsigned short* AL,
                         hipStream_t st) {
  int total4 = M * K / 4;
  packa_kernel<<<(total4 + 255) / 256, 256, 0, st>>>(A, lda, K, total4, AH, AL);
}

static inline void pack_depth(const float* wq, const float* wk, const float* wv, const float* wo,
                              const float* w1, const float* w2,
                              unsigned short* qkvH, unsigned short* qkvL,
                              unsigned short* woH, unsigned short* woL,
                              unsigned short* w1H, unsigned short* w1L,
                              unsigned short* w2H, unsigned short* w2L, hipStream_t st) {
  PackAll pa;
  int blk = 0;
  auto add = [&](int i, const float* W, unsigned short* WH, unsigned short* WL, int K, int N) {
    int nbx = (N + 63) / 64, nby = (K + 63) / 64;
    pa.d[i] = {W, WH, WL, K, N, nbx, blk};
    blk += nbx * nby;
  };
  add(0, wq, qkvH + 0,      qkvL + 0,      ROI, ROI);
  add(1, wk, qkvH + 160000, qkvL + 160000, ROI, ROI);
  add(2, wv, qkvH + 320000, qkvL + 320000, ROI, ROI);
  add(3, wo, woH, woL, ROI, ROI);
  add(4, w1, w1H, w1L, ROI, HIDF);
  add(5, w2, w2H, w2L, HIDF, ROI);
  packall_kernel<<<blk, 256, 0, st>>>(pa);
}

extern "C" void kernel_launch(void* const* d_in, const int* in_sizes, int n_in,
                              void* d_out, int out_size, void* d_ws, size_t ws_size,
                              hipStream_t stream) {
  const float* in  = (const float*)d_in[0];
  const float* sel = (const float*)d_in[1];
  const float* wq  = (const float*)d_in[2];
  const float* wk  = (const float*)d_in[3];
  const float* wv  = (const float*)d_in[4];
  const float* wo  = (const float*)d_in[5];
  const float* bo  = (const float*)d_in[6];
  const float* w1  = (const float*)d_in[7];
  const float* b1  = (const float*)d_in[8];
  const float* w2  = (const float*)d_in[9];
  const float* b2  = (const float*)d_in[10];
  const float* lng = (const float*)d_in[11];
  const float* lnb = (const float*)d_in[12];
  const float* pws = (const float*)d_in[13];
  const float* pwf = (const float*)d_in[14];
  const float* pmw = (const float*)d_in[15];
  const float* pmb = (const float*)d_in[16];
  const float* r1w = (const float*)d_in[17];
  const float* r1b = (const float*)d_in[18];
  const float* r2w = (const float*)d_in[19];
  const float* r2b = (const float*)d_in[20];
  float* out = (float*)d_out;

  float* ws = (float*)d_ws;
  const size_t AT = (size_t)NB * ROI * ROI;  // 10,240,000 floats per slab

  unsigned short* up = (unsigned short*)ws;
  unsigned short* qkvH = up;                 // [1200][400]
  unsigned short* qkvL = up + 480000;
  unsigned short* woH  = up + 960000;        // [400][400]
  unsigned short* woL  = up + 1120000;
  unsigned short* w1H  = up + 1280000;       // [800][400]
  unsigned short* w1L  = up + 1600000;
  unsigned short* w2H  = up + 1920000;       // [400][800]
  unsigned short* w2L  = up + 2240000;       // ends 2.88M u16 < 1 slab

  float* smalls = ws + 6 * AT;
  float* meanb = smalls;
  float* stdb  = smalls + 64;
  float* scores = smalls + 128;
  int*   idx = (int*)(smalls + 128 + NB * ROI);
  float* probs = smalls + 128 + NB * ROI + NB * KPOOL;
  double* pp = (double*)(smalls + 128 + NB * ROI + NB * KPOOL + 2 * NB * NC + 16);

  float* Mmask = ws + AT;

  pre_partial_kernel<<<dim3(NB, CTT), 256, 0, stream>>>(in, pp);
  pre_final_kernel<<<1, 64, 0, stream>>>(pp, meanb, stdb);
  build_m_kernel<<<(int)((AT + 255) / 256), 256, 0, stream>>>(in, sel, meanb, stdb, Mmask);

  // ---------------- depth 0: N=400, Mtok=25600
  {
    const int N = ROI;
    const int Mtok = NB * N;  // 25600
    pack_depth(wq, wk, wv, wo, w1, w2, qkvH, qkvL, woH, woL, w1H, w1L, w2H, w2L, stream);

    unsigned short* AinH = (unsigned short*)(ws + 5 * AT);
    unsigned short* AinL = AinH + (size_t)Mtok * ROI;
    packa(in, 2 * ROI, Mtok, ROI, AinH, AinL, stream);

    unsigned short* QKVH_ = (unsigned short*)(ws + 2 * AT);          // [2AT,5AT)
    unsigned short* QKVL_ = QKVH_ + (size_t)Mtok * (3 * ROI);
    mgemm<6>(AinH, AinL, qkvH, qkvL, nullptr, nullptr, 0, nullptr, QKVH_, QKVL_,
             Mtok, 3 * ROI, ROI, stream);

    unsigned short* OpH = (unsigned short*)(ws + 5 * AT);            // over Ain planes (dead)
    unsigned short* OpL = OpH + (size_t)Mtok * ROI;
    fattn_kernel<<<dim3((N + FBI - 1) / FBI, HEADS, NB), 512, 0, stream>>>(
        QKVH_, QKVL_, Mmask, OpH, OpL, N);

    float* Xa0 = ws + 2 * AT;                                        // over QKV planes (dead)
    unsigned short* XaH = (unsigned short*)(ws + 3 * AT);
    unsigned short* XaL = XaH + (size_t)Mtok * ROI;
    mgemm<5>(OpH, OpL, woH, woL, bo, in, 2 * ROI, Xa0, XaH, XaL,
             Mtok, ROI, ROI, stream);

    unsigned short* Hh = (unsigned short*)(ws + 4 * AT);             // [4AT,5AT)
    unsigned short* Hl = (unsigned short*)(ws + 5 * AT);             // [5AT,6AT) — Op dead
    mgemm<4>(XaH, XaL, w1H, w1L, b1, nullptr, 0, nullptr, Hh, Hl,
             Mtok, HIDF, ROI, stream);

    float* Y0 = ws + 3 * AT;                                         // over Xa planes (dead)
    mgemm<2>(Hh, Hl, w2H, w2L, b2, Xa0, ROI, Y0, nullptr, nullptr,
             Mtok, ROI, HIDF, stream);

    float* Xn = ws + 2 * AT;                                         // over Xa0 (dead)
    ln_kernel<<<Mtok, 128, 0, stream>>>(Y0, lng, lnb, Xn);

    float* gfp0 = ws + 3 * AT;                                       // over Y0 (dead)
    colmean_kernel<<<dim3(NB, CTT), 128, 0, stream>>>(Xn, gfp0, N);
    head_kernel<<<NB, 128, 0, stream>>>(gfp0, r1w, r1b, r2w, r2b, probs, N);

    score_kernel<<<dim3(ROI, NB), 128, 0, stream>>>(Mmask, Xn, pws, pwf, pmw, pmb, scores);
    select_kernel<<<NB, 128, 0, stream>>>(scores, idx);
    float* Mp = ws + 4 * AT + 1200000;                               // over Hh (dead)
    gatherm_kernel<<<NB * KPOOL, 128, 0, stream>>>(Mmask, idx, Mp);  // Mmask last use
    float* Xp = ws + 5 * AT;                                         // over Hl (dead)
    unsigned short* XpH = (unsigned short*)(ws + AT);                // over Mmask (dead)
    unsigned short* XpL = XpH + (size_t)NB * KPOOL * ROI;
    gatherx_kernel<<<NB * KPOOL, 128, 0, stream>>>(Xn, scores, idx, Xp, XpH, XpL);
  }

  // ---------------- depth 1: N=280, Mtok=17920
  {
    const int N = KPOOL;
    const int Mtok = NB * N;  // 17920
    const int d = 1;
    const float* wq1 = wq + (size_t)d * ROI * ROI;
    const float* wk1 = wk + (size_t)d * ROI * ROI;
    const float* wv1 = wv + (size_t)d * ROI * ROI;
    const float* wo1 = wo + (size_t)d * ROI * ROI;
    const float* bo1 = bo + (size_t)d * ROI;
    const float* w11 = w1 + (size_t)d * ROI * HIDF;
    const float* b11 = b1 + (size_t)d * HIDF;
    const float* w21 = w2 + (size_t)d * HIDF * ROI;
    const float* b21 = b2 + (size_t)d * ROI;
    const float* lng1 = lng + (size_t)d * ROI;
    const float* lnb1 = lnb + (size_t)d * ROI;
    const float* r1w1 = r1w + (size_t)d * ROI * 128;
    const float* r1b1 = r1b + (size_t)d * 128;
    const float* r2w1 = r2w + (size_t)d * 128 * NC;
    const float* r2b1 = r2b + (size_t)d * NC;

    float* Xp = ws + 5 * AT;
    float* Mp = ws + 4 * AT + 1200000;
    unsigned short* XpH = (unsigned short*)(ws + AT);
    unsigned short* XpL = XpH + (size_t)Mtok * ROI;

    pack_depth(wq1, wk1, wv1, wo1, w11, w21, qkvH, qkvL, woH, woL, w1H, w1L, w2H, w2L, stream);

    unsigned short* QKVH_ = (unsigned short*)(ws + 2 * AT);          // ends before Mp
    unsigned short* QKVL_ = QKVH_ + (size_t)Mtok * (3 * ROI);
    mgemm<6>(XpH, XpL, qkvH, qkvL, nullptr, nullptr, 0, nullptr, QKVH_, QKVL_,
             Mtok, 3 * ROI, ROI, stream);

    unsigned short* OpH = (unsigned short*)(ws + AT);                // over Xp planes (dead)
    unsigned short* OpL = OpH + (size_t)Mtok * ROI;
    fattn_kernel<<<dim3((N + FBI - 1) / FBI, HEADS, NB), 512, 0, stream>>>(
        QKVH_, QKVL_, Mp, OpH, OpL, N);

    float* Xa1 = ws + 2 * AT;                                        // over QKV planes (dead)
    unsigned short* XaH = (unsigned short*)(ws + 3 * AT);
    unsigned short* XaL = XaH + (size_t)Mtok * ROI;
    mgemm<5>(OpH, OpL, woH, woL, bo1, Xp, ROI, Xa1, XaH, XaL,
             Mtok, ROI, ROI, stream);

    unsigned short* H1h = (unsigned short*)(ws + 4 * AT);            // Mp dead after fattn
    unsigned short* H1l = (unsigned short*)(ws + 5 * AT);            // Xp dead after Xa1
    mgemm<4>(XaH, XaL, w1H, w1L, b11, nullptr, 0, nullptr, H1h, H1l,
             Mtok, HIDF, ROI, stream);

    float* Y1 = ws + AT;                                             // over Op planes (dead)
    mgemm<2>(H1h, H1l, w2H, w2L, b21, Xa1, ROI, Y1, nullptr, nullptr,
             Mtok, ROI, HIDF, stream);

    float* Xf = ws + 3 * AT;                                         // over Xa planes (dead)
    ln_kernel<<<Mtok, 128, 0, stream>>>(Y1, lng1, lnb1, Xf);

    float* gfp1 = ws + 2 * AT;                                       // over Xa1 (dead)
    colmean_kernel<<<dim3(NB, CTT), 128, 0, stream>>>(Xf, gfp1, N);
    head_kernel<<<NB, 128, 0, stream>>>(gfp1, r1w1, r1b1, r2w1, r2b1, probs + NB * NC, N);
    finalize_kernel<<<NB, 128, 0, stream>>>(gfp1, probs, out, N);
  }
  (void)in_sizes; (void)n_in; (void)out_size; (void)ws_size;
}

// Round 12
// 1574.461 us; speedup vs baseline: 1.0617x; 1.0617x over previous
//
#include <hip/hip_runtime.h>
#include <math.h>

#define ROI 400
#define HEADS 4
#define DH 100
#define NB 64
#define HIDF 800
#define NC 2
#define KPOOL 280
#define ATT_SCALE 0.1f
#define CTT 10

typedef __attribute__((ext_vector_type(8))) short short8v;
typedef __attribute__((ext_vector_type(8))) unsigned short u16x8;
typedef __attribute__((ext_vector_type(4))) float f32x4;

union U8 { short8v v; unsigned short u[8]; };

__device__ __forceinline__ unsigned short f2bf(float x) {
  unsigned int u = __float_as_uint(x);
  u += 0x7fffu + ((u >> 16) & 1u);
  return (unsigned short)(u >> 16);
}
__device__ __forceinline__ void split2(float x, unsigned short& h, unsigned short& l) {
  h = f2bf(x);
  float hf = __uint_as_float(((unsigned int)h) << 16);
  l = f2bf(x - hf);
}

// ---------------------------------------------------------------- preprocess (two-stage)
__global__ __launch_bounds__(256) void pre_partial_kernel(const float* __restrict__ in,
                                                          double* __restrict__ pp) {
  int b = blockIdx.x, t = blockIdx.y;
  const float* p = in + (size_t)b * ROI * (2 * ROI);
  float s = 0.f, ss = 0.f;
  for (int e = threadIdx.x; e < 40 * ROI; e += 256) {
    int r = 40 * t + e / ROI, c = e % ROI;
    float v = log10f(p[(size_t)r * (2 * ROI) + ROI + c] + 1.0f);
    s += v; ss += v * v;
  }
  __shared__ double rs[256], rss[256];
  rs[threadIdx.x] = s; rss[threadIdx.x] = ss;
  __syncthreads();
  for (int st = 128; st > 0; st >>= 1) {
    if (threadIdx.x < st) { rs[threadIdx.x] += rs[threadIdx.x + st]; rss[threadIdx.x] += rss[threadIdx.x + st]; }
    __syncthreads();
  }
  if (threadIdx.x == 0) {
    pp[(b * CTT + t) * 2 + 0] = rs[0];
    pp[(b * CTT + t) * 2 + 1] = rss[0];
  }
}

__global__ __launch_bounds__(64) void pre_final_kernel(const double* __restrict__ pp,
                                                       float* __restrict__ meanb,
                                                       float* __restrict__ stdb) {
  int b = threadIdx.x;
  double s = 0.0, ss = 0.0;
  for (int t = 0; t < CTT; ++t) { s += pp[(b * CTT + t) * 2]; ss += pp[(b * CTT + t) * 2 + 1]; }
  const int n = ROI * ROI;
  double mean = s / n;
  double var = (ss - s * s / n) / (double)(n - 1);
  meanb[b] = (float)mean;
  stdb[b]  = (float)(sqrt(var) + 1e-6);
}

__global__ __launch_bounds__(256) void build_m_kernel(const float* __restrict__ in,
                                                      const float* __restrict__ sel,
                                                      const float* __restrict__ meanb,
                                                      const float* __restrict__ stdb,
                                                      float* __restrict__ M) {
  size_t e = (size_t)blockIdx.x * blockDim.x + threadIdx.x;
  const size_t total = (size_t)NB * ROI * ROI;
  if (e >= total) return;
  int c = (int)(e % ROI);
  int r = (int)((e / ROI) % ROI);
  int b = (int)(e / ((size_t)ROI * ROI));
  const float* row = in + ((size_t)b * ROI + r) * (2 * ROI);
  float v = log10f(row[ROI + c] + 1.0f);
  float sg = 1.0f / (1.0f + expf(-sel[r * ROI + c]));
  M[e] = ((v - meanb[b]) / stdb[b]) * sg;
}

// ---------------------------------------------------------------- batched weight pack (one launch / depth)
struct PackDesc {
  const float* W;
  unsigned short* WH;
  unsigned short* WL;
  int K, N, nbx, blk0;
};
struct PackAll { PackDesc d[6]; };

__global__ __launch_bounds__(256) void packall_kernel(PackAll pa) {
  int gb = blockIdx.x;
  int i = 0;
#pragma unroll
  for (int j = 1; j < 6; ++j) if (gb >= pa.d[j].blk0) i = j;
  const float* __restrict__ W = pa.d[i].W;
  unsigned short* __restrict__ WH = pa.d[i].WH;
  unsigned short* __restrict__ WL = pa.d[i].WL;
  const int K = pa.d[i].K, N = pa.d[i].N;
  int lb = gb - pa.d[i].blk0;
  int bn = (lb % pa.d[i].nbx) * 64;
  int bk = (lb / pa.d[i].nbx) * 64;

  __shared__ float t[64][68];
  int r = threadIdx.x >> 2;
  int c0 = (threadIdx.x & 3) << 4;
  int gk = bk + r;
#pragma unroll
  for (int q = 0; q < 4; ++q) {
    int c = c0 + 4 * q;
    float4 v = make_float4(0.f, 0.f, 0.f, 0.f);
    if (gk < K && bn + c < N) v = *(const float4*)(W + (size_t)gk * N + bn + c);
    *(float4*)&t[r][c] = v;
  }
  __syncthreads();
  int gn = bn + r;
#pragma unroll
  for (int q = 0; q < 4; ++q) {
    int c = c0 + 4 * q;
    int gkk = bk + c;
    if (gn < N && gkk < K) {
      ushort4 h, l;
      split2(t[c + 0][r], h.x, l.x);
      split2(t[c + 1][r], h.y, l.y);
      split2(t[c + 2][r], h.z, l.z);
      split2(t[c + 3][r], h.w, l.w);
      *(ushort4*)(WH + (size_t)gn * K + gkk) = h;
      *(ushort4*)(WL + (size_t)gn * K + gkk) = l;
    }
  }
}

// ---------------------------------------------------------------- activation pack
__global__ __launch_bounds__(256) void packa_kernel(const float* __restrict__ A, int lda, int K, int total4,
                                                    unsigned short* __restrict__ AH,
                                                    unsigned short* __restrict__ AL) {
  int e = blockIdx.x * 256 + threadIdx.x;
  if (e >= total4) return;
  int idx = e << 2;
  int row = idx / K, k = idx - row * K;
  float4 v = *(const float4*)(A + (size_t)row * lda + k);
  ushort4 h, l;
  split2(v.x, h.x, l.x); split2(v.y, h.y, l.y);
  split2(v.z, h.z, l.z); split2(v.w, h.w, l.w);
  *(ushort4*)(AH + (size_t)row * K + k) = h;
  *(ushort4*)(AL + (size_t)row * K + k) = l;
}

// ---------------------------------------------------------------- MFMA split-bf16 GEMM
// EPI: 0 plain float, 2 bias+res float, 4 bias+gelu -> split out, 5 bias+res -> float+split, 6 plain -> split out
#define TBM 128
#define TBN 128
#define TBK 32
#define KP 40

template<int EPI>
__global__ __launch_bounds__(256) void mgemm_kernel(const unsigned short* __restrict__ AHp,
                                                    const unsigned short* __restrict__ ALp,
                                                    const unsigned short* __restrict__ WH,
                                                    const unsigned short* __restrict__ WL,
                                                    const float* __restrict__ bias,
                                                    const float* __restrict__ res, int ldr,
                                                    float* __restrict__ C,
                                                    unsigned short* __restrict__ CH,
                                                    unsigned short* __restrict__ CL,
                                                    int M, int N, int K) {
  __shared__ unsigned short Ah[TBM][KP], Al[TBM][KP], Bh[TBN][KP], Bl[TBN][KP];
  const int tid = threadIdx.x;
  const int lane = tid & 63;
  const int wid = tid >> 6;
  const int wm = wid >> 1, wn = wid & 1;
  const int l15 = lane & 15, l4 = lane >> 4;
  const int bm = blockIdx.y * TBM;
  const int bn = blockIdx.x * TBN;

  f32x4 acc[4][4];
#pragma unroll
  for (int i = 0; i < 4; ++i)
#pragma unroll
    for (int j = 0; j < 4; ++j) acc[i][j] = (f32x4){0.f, 0.f, 0.f, 0.f};

  for (int k0 = 0; k0 < K; k0 += TBK) {
#pragma unroll
    for (int it = 0; it < 2; ++it) {
      int c = tid + 256 * it;
      int row = c >> 2;
      int kq = (c & 3) << 3;
      u16x8 vh = {0, 0, 0, 0, 0, 0, 0, 0};
      u16x8 vl = {0, 0, 0, 0, 0, 0, 0, 0};
      if (k0 + kq + 8 <= K) {
        size_t off = (size_t)(bm + row) * K + k0 + kq;
        vh = *(const u16x8*)(AHp + off);
        vl = *(const u16x8*)(ALp + off);
      }
      *(u16x8*)&Ah[row][kq] = vh;
      *(u16x8*)&Al[row][kq] = vl;
    }
#pragma unroll
    for (int it = 0; it < 2; ++it) {
      int c = tid + 256 * it;
      int row = c >> 2;
      int kq = (c & 3) << 3;
      int gn = bn + row;
      u16x8 vh = {0, 0, 0, 0, 0, 0, 0, 0};
      u16x8 vl = {0, 0, 0, 0, 0, 0, 0, 0};
      if (gn < N && k0 + kq + 8 <= K) {
        size_t off = (size_t)gn * K + k0 + kq;
        vh = *(const u16x8*)(WH + off);
        vl = *(const u16x8*)(WL + off);
      }
      *(u16x8*)&Bh[row][kq] = vh;
      *(u16x8*)&Bl[row][kq] = vl;
    }
    __syncthreads();

    short8v ah[4], alo[4], bh[4], blo[4];
#pragma unroll
    for (int mf = 0; mf < 4; ++mf) {
      int r = wm * 64 + mf * 16 + l15;
      ah[mf]  = *(const short8v*)&Ah[r][l4 * 8];
      alo[mf] = *(const short8v*)&Al[r][l4 * 8];
    }
#pragma unroll
    for (int nf = 0; nf < 4; ++nf) {
      int r = wn * 64 + nf * 16 + l15;
      bh[nf]  = *(const short8v*)&Bh[r][l4 * 8];
      blo[nf] = *(const short8v*)&Bl[r][l4 * 8];
    }
#pragma unroll
    for (int mf = 0; mf < 4; ++mf)
#pragma unroll
      for (int nf = 0; nf < 4; ++nf) {
        acc[mf][nf] = __builtin_amdgcn_mfma_f32_16x16x32_bf16(ah[mf], bh[nf], acc[mf][nf], 0, 0, 0);
        acc[mf][nf] = __builtin_amdgcn_mfma_f32_16x16x32_bf16(ah[mf], blo[nf], acc[mf][nf], 0, 0, 0);
        acc[mf][nf] = __builtin_amdgcn_mfma_f32_16x16x32_bf16(alo[mf], bh[nf], acc[mf][nf], 0, 0, 0);
      }
    __syncthreads();
  }

#pragma unroll
  for (int mf = 0; mf < 4; ++mf) {
#pragma unroll
    for (int nf = 0; nf < 4; ++nf) {
      int col = bn + wn * 64 + nf * 16 + l15;
      if (col < N) {
        float bv = (EPI >= 1 && EPI != 6) ? bias[col] : 0.f;
        int row0 = bm + wm * 64 + mf * 16 + l4 * 4;
#pragma unroll
        for (int r = 0; r < 4; ++r) {
          float v = acc[mf][nf][r] + bv;
          int row = row0 + r;
          if (EPI == 2 || EPI == 5) v += res[(size_t)row * ldr + col];
          if (EPI == 4) {
            v = 0.5f * v * (1.0f + erff(v * 0.70710678118654752f));
            unsigned short hh, ll;
            split2(v, hh, ll);
            CH[(size_t)row * N + col] = hh;
            CL[(size_t)row * N + col] = ll;
          } else if (EPI == 5) {
            C[(size_t)row * N + col] = v;
            unsigned short hh, ll;
            split2(v, hh, ll);
            CH[(size_t)row * N + col] = hh;
            CL[(size_t)row * N + col] = ll;
          } else if (EPI == 6) {
            unsigned short hh, ll;
            split2(v, hh, ll);
            CH[(size_t)row * N + col] = hh;
            CL[(size_t)row * N + col] = ll;
          } else {
            C[(size_t)row * N + col] = v;
          }
        }
      }
    }
  }
}

// ---------------------------------------------------------------- MFMA flash attention (BI=64, XCD-local grid)
// grid = (NB*HEADS, n_iblocks): same-(b,h) blocks sit at linear stride 256 (≡0 mod 8)
// -> land on the same XCD -> K/V stays L2-hot across iblocks.
#define FBJ 32

__global__ __launch_bounds__(256) void fattn_kernel(const unsigned short* __restrict__ QKVH,
                                                    const unsigned short* __restrict__ QKVL,
                                                    const float* __restrict__ Mm,
                                                    unsigned short* __restrict__ OH,
                                                    unsigned short* __restrict__ OL, int N) {
  const int ldq = 3 * ROI;
  __shared__ unsigned short Kh[FBJ][136], Kl[FBJ][136];
  __shared__ unsigned short Vth[112][40], Vtl[112][40];
  __shared__ unsigned short Ph[64][40], Pl[64][40];

  const int tid = threadIdx.x;
  const int lane = tid & 63;
  const int w = tid >> 6;
  const int l15 = lane & 15, l4 = lane >> 4;
  const int h = blockIdx.x & (HEADS - 1);
  const int b = blockIdx.x >> 2;
  const int i0 = blockIdx.y * 64;

  const float* Mb = Mm + (size_t)b * N * N;

  for (int e = tid; e < 12 * 40; e += 256) {
    Vth[100 + e / 40][e % 40] = 0; Vtl[100 + e / 40][e % 40] = 0;
  }

  // Q fragments straight from split planes
  int qr = i0 + 16 * w + l15; if (qr >= N) qr = N - 1;
  const unsigned short* qrH = QKVH + ((size_t)b * N + qr) * ldq + h * DH;
  const unsigned short* qrL = QKVL + ((size_t)b * N + qr) * ldq + h * DH;
  short8v qh[4], ql[4];
#pragma unroll
  for (int kg = 0; kg < 4; ++kg) {
    int d0v = kg * 32 + l4 * 8;
    U8 th, tl;
    if (d0v + 8 <= DH) {
      *(ushort4*)&th.u[0] = *(const ushort4*)(qrH + d0v);
      *(ushort4*)&th.u[4] = *(const ushort4*)(qrH + d0v + 4);
      *(ushort4*)&tl.u[0] = *(const ushort4*)(qrL + d0v);
      *(ushort4*)&tl.u[4] = *(const ushort4*)(qrL + d0v + 4);
    } else if (d0v < DH) {
      *(ushort4*)&th.u[0] = *(const ushort4*)(qrH + d0v);
      *(ushort4*)&tl.u[0] = *(const ushort4*)(qrL + d0v);
#pragma unroll
      for (int j = 4; j < 8; ++j) { th.u[j] = 0; tl.u[j] = 0; }
    } else {
#pragma unroll
      for (int j = 0; j < 8; ++j) { th.u[j] = 0; tl.u[j] = 0; }
    }
    qh[kg] = th.v; ql[kg] = tl.v;
  }

  float m_i[4], l_i[4];
  f32x4 o[7];
#pragma unroll
  for (int r = 0; r < 4; ++r) { m_i[r] = -INFINITY; l_i[r] = 0.f; }
#pragma unroll
  for (int ff = 0; ff < 7; ++ff) o[ff] = (f32x4){0.f, 0.f, 0.f, 0.f};

  const int njt = (N + FBJ - 1) / FBJ;
  for (int jt = 0; jt < njt; ++jt) {
    const int j0 = jt * FBJ;
    const int kv0 = j0 + l15, kv1 = j0 + l15 + 16;

    // prefetch M tile into registers (hidden under staging + QK^T)
    float mpre[4][2];
#pragma unroll
    for (int r = 0; r < 4; ++r) {
      int gq = i0 + 16 * w + l4 * 4 + r;
      int gqc = (gq < N) ? gq : N - 1;
      const float* Mr = Mb + (size_t)gqc * N;
      mpre[r][0] = (kv0 < N) ? Mr[kv0] : 0.f;
      mpre[r][1] = (kv1 < N) ? Mr[kv1] : 0.f;
    }

    __syncthreads();
    // stage K: pure ushort4 copies from planes
    for (int e = tid; e < 32 * 32; e += 256) {
      int kv = e >> 5;
      int dq = (e & 31) << 2;
      int gj = j0 + kv; if (gj >= N) gj = N - 1;
      size_t off = ((size_t)b * N + gj) * ldq + ROI + h * DH + dq;
      ushort4 hh = {0, 0, 0, 0}, ll = {0, 0, 0, 0};
      if (dq < DH) { hh = *(const ushort4*)(QKVH + off); ll = *(const ushort4*)(QKVL + off); }
      *(ushort4*)&Kh[kv][dq] = hh;
      *(ushort4*)&Kl[kv][dq] = ll;
    }
    // stage V transposed: ushort4 loads + OR/shift packs, conflict-free u32 stores
    for (int e = tid; e < 400; e += 256) {
      int kvp = e & 15;
      int dq = (e >> 4) << 2;
      int gj0 = j0 + 2 * kvp;     if (gj0 >= N) gj0 = N - 1;
      int gj1 = j0 + 2 * kvp + 1; if (gj1 >= N) gj1 = N - 1;
      size_t o0 = ((size_t)b * N + gj0) * ldq + 2 * ROI + h * DH + dq;
      size_t o1 = ((size_t)b * N + gj1) * ldq + 2 * ROI + h * DH + dq;
      ushort4 aH = *(const ushort4*)(QKVH + o0);
      ushort4 bH = *(const ushort4*)(QKVH + o1);
      ushort4 aL = *(const ushort4*)(QKVL + o0);
      ushort4 bL = *(const ushort4*)(QKVL + o1);
      *(unsigned int*)&Vth[dq + 0][2 * kvp] = (unsigned int)aH.x | ((unsigned int)bH.x << 16);
      *(unsigned int*)&Vth[dq + 1][2 * kvp] = (unsigned int)aH.y | ((unsigned int)bH.y << 16);
      *(unsigned int*)&Vth[dq + 2][2 * kvp] = (unsigned int)aH.z | ((unsigned int)bH.z << 16);
      *(unsigned int*)&Vth[dq + 3][2 * kvp] = (unsigned int)aH.w | ((unsigned int)bH.w << 16);
      *(unsigned int*)&Vtl[dq + 0][2 * kvp] = (unsigned int)aL.x | ((unsigned int)bL.x << 16);
      *(unsigned int*)&Vtl[dq + 1][2 * kvp] = (unsigned int)aL.y | ((unsigned int)bL.y << 16);
      *(unsigned int*)&Vtl[dq + 2][2 * kvp] = (unsigned int)aL.z | ((unsigned int)bL.z << 16);
      *(unsigned int*)&Vtl[dq + 3][2 * kvp] = (unsigned int)aL.w | ((unsigned int)bL.w << 16);
    }
    __syncthreads();

    f32x4 sacc[2];
    sacc[0] = (f32x4){0.f, 0.f, 0.f, 0.f};
    sacc[1] = (f32x4){0.f, 0.f, 0.f, 0.f};
#pragma unroll
    for (int kg = 0; kg < 4; ++kg) {
#pragma unroll
      for (int f = 0; f < 2; ++f) {
        short8v bh = *(const short8v*)&Kh[l15 + 16 * f][kg * 32 + l4 * 8];
        short8v bl = *(const short8v*)&Kl[l15 + 16 * f][kg * 32 + l4 * 8];
        sacc[f] = __builtin_amdgcn_mfma_f32_16x16x32_bf16(qh[kg], bh, sacc[f], 0, 0, 0);
        sacc[f] = __builtin_amdgcn_mfma_f32_16x16x32_bf16(qh[kg], bl, sacc[f], 0, 0, 0);
        sacc[f] = __builtin_amdgcn_mfma_f32_16x16x32_bf16(ql[kg], bh, sacc[f], 0, 0, 0);
      }
    }

#pragma unroll
    for (int r = 0; r < 4; ++r) {
      float s0 = (kv0 < N) ? sacc[0][r] * ATT_SCALE * (1.0f + mpre[r][0]) : -INFINITY;
      float s1 = (kv1 < N) ? sacc[1][r] * ATT_SCALE * (1.0f + mpre[r][1]) : -INFINITY;
      float rm = fmaxf(s0, s1);
      rm = fmaxf(rm, __shfl_xor(rm, 1, 16));
      rm = fmaxf(rm, __shfl_xor(rm, 2, 16));
      rm = fmaxf(rm, __shfl_xor(rm, 4, 16));
      rm = fmaxf(rm, __shfl_xor(rm, 8, 16));
      float nm = fmaxf(m_i[r], rm);
      float fr = expf(m_i[r] - nm);
      float p0 = (kv0 < N) ? expf(s0 - nm) : 0.f;
      float p1 = (kv1 < N) ? expf(s1 - nm) : 0.f;
      float ts = p0 + p1;
      ts += __shfl_xor(ts, 1, 16);
      ts += __shfl_xor(ts, 2, 16);
      ts += __shfl_xor(ts, 4, 16);
      ts += __shfl_xor(ts, 8, 16);
      l_i[r] = l_i[r] * fr + ts;
      m_i[r] = nm;
#pragma unroll
      for (int ff = 0; ff < 7; ++ff) o[ff][r] *= fr;
      unsigned short h0, l0, h1, l1;
      split2(p0, h0, l0); split2(p1, h1, l1);
      int prow = 16 * w + l4 * 4 + r;
      Ph[prow][l15] = h0;      Pl[prow][l15] = l0;
      Ph[prow][l15 + 16] = h1; Pl[prow][l15 + 16] = l1;
    }
    __syncthreads();

    short8v ph = *(const short8v*)&Ph[16 * w + l15][l4 * 8];
    short8v pl = *(const short8v*)&Pl[16 * w + l15][l4 * 8];
#pragma unroll
    for (int ff = 0; ff < 7; ++ff) {
      short8v vh = *(const short8v*)&Vth[ff * 16 + l15][l4 * 8];
      short8v vl = *(const short8v*)&Vtl[ff * 16 + l15][l4 * 8];
      o[ff] = __builtin_amdgcn_mfma_f32_16x16x32_bf16(ph, vh, o[ff], 0, 0, 0);
      o[ff] = __builtin_amdgcn_mfma_f32_16x16x32_bf16(ph, vl, o[ff], 0, 0, 0);
      o[ff] = __builtin_amdgcn_mfma_f32_16x16x32_bf16(pl, vh, o[ff], 0, 0, 0);
    }
  }

#pragma unroll
  for (int r = 0; r < 4; ++r) {
    int gq = i0 + 16 * w + l4 * 4 + r;
    if (gq < N) {
      float inv = 1.0f / l_i[r];
      size_t rowoff = ((size_t)b * N + gq) * ROI + h * DH;
#pragma unroll
      for (int ff = 0; ff < 7; ++ff) {
        int d = ff * 16 + l15;
        if (d < DH) {
          unsigned short hh, ll;
          split2(o[ff][r] * inv, hh, ll);
          OH[rowoff + d] = hh;
          OL[rowoff + d] = ll;
        }
      }
    }
  }
}

// ---------------------------------------------------------------- layernorm
__global__ __launch_bounds__(128) void ln_kernel(const float* __restrict__ Y, const float* __restrict__ g,
                                                 const float* __restrict__ bta, float* __restrict__ X) {
  int row = blockIdx.x;
  const float* y = Y + (size_t)row * ROI;
  float* x = X + (size_t)row * ROI;
  int tid = threadIdx.x;
  __shared__ float red[128];
  float s = 0.f;
  for (int c = tid; c < ROI; c += 128) s += y[c];
  red[tid] = s; __syncthreads();
  for (int st = 64; st > 0; st >>= 1) { if (tid < st) red[tid] += red[tid + st]; __syncthreads(); }
  float mu = red[0] / ROI;
  __syncthreads();
  float v = 0.f;
  for (int c = tid; c < ROI; c += 128) { float d = y[c] - mu; v += d * d; }
  red[tid] = v; __syncthreads();
  for (int st = 64; st > 0; st >>= 1) { if (tid < st) red[tid] += red[tid + st]; __syncthreads(); }
  float rstd = rsqrtf(red[0] / ROI + 1e-5f);
  for (int c = tid; c < ROI; c += 128) x[c] = (y[c] - mu) * rstd * g[c] + bta[c];
}

// ---------------------------------------------------------------- column-mean partials
__global__ __launch_bounds__(128) void colmean_kernel(const float* __restrict__ X,
                                                      float* __restrict__ gfp, int N) {
  int b = blockIdx.x, t = blockIdx.y, tid = threadIdx.x;
  int per = (N + CTT - 1) / CTT;
  int n0 = t * per, n1 = n0 + per;
  if (n1 > N) n1 = N;
  float a0 = 0.f, a1 = 0.f, a2 = 0.f, a3 = 0.f;
  for (int n = n0; n < n1; ++n) {
    const float* row = X + ((size_t)b * N + n) * ROI;
    a0 += row[tid]; a1 += row[tid + 128]; a2 += row[tid + 256];
    if (tid < 16) a3 += row[tid + 384];
  }
  float* g = gfp + ((size_t)b * CTT + t) * ROI;
  g[tid] = a0; g[tid + 128] = a1; g[tid + 256] = a2;
  if (tid < 16) g[tid + 384] = a3;
}

// ---------------------------------------------------------------- classifier head (from partials)
__global__ __launch_bounds__(128) void head_kernel(const float* __restrict__ gfp,
                                                   const float* __restrict__ r1w, const float* __restrict__ r1b,
                                                   const float* __restrict__ r2w, const float* __restrict__ r2b,
                                                   float* __restrict__ probs, int N) {
  int b = blockIdx.x, tid = threadIdx.x;
  __shared__ float gf[ROI];
  __shared__ float hid[128];
  for (int c = tid; c < ROI; c += 128) {
    float s = 0.f;
    for (int t = 0; t < CTT; ++t) s += gfp[((size_t)b * CTT + t) * ROI + c];
    gf[c] = s / (float)N;
  }
  __syncthreads();
  {
    float a = r1b[tid];
    for (int k = 0; k < ROI; ++k) a += gf[k] * r1w[k * 128 + tid];
    hid[tid] = (a >= 0.f) ? a : 0.01f * a;
  }
  __syncthreads();
  if (tid < NC) {
    float l = r2b[tid];
    for (int k = 0; k < 128; ++k) l += hid[k] * r2w[k * NC + tid];
    gf[tid] = l;
  }
  __syncthreads();
  if (tid == 0) {
    float m = fmaxf(gf[0], gf[1]);
    float e0 = expf(gf[0] - m), e1 = expf(gf[1] - m);
    float inv = 1.f / (e0 + e1);
    probs[b * NC + 0] = e0 * inv;
    probs[b * NC + 1] = e1 * inv;
  }
}

// ---------------------------------------------------------------- final output (from partials)
__global__ __launch_bounds__(128) void finalize_kernel(const float* __restrict__ gfp,
                                                       const float* __restrict__ probs,
                                                       float* __restrict__ out, int N) {
  int b = blockIdx.x, tid = threadIdx.x;
  __shared__ float f[ROI];
  __shared__ float red[128];
  for (int c = tid; c < ROI; c += 128) {
    float s = 0.f;
    for (int t = 0; t < CTT; ++t) s += gfp[((size_t)b * CTT + t) * ROI + c];
    f[c] = s / (float)N;
  }
  __syncthreads();
  float ls = 0.f;
  for (int c = tid; c < ROI; c += 128) ls += f[c] * f[c];
  red[tid] = ls; __syncthreads();
  for (int st = 64; st > 0; st >>= 1) { if (tid < st) red[tid] += red[tid + st]; __syncthreads(); }
  float inv = 1.f / fmaxf(sqrtf(red[0]), 1e-12f);
  for (int c = tid; c < ROI; c += 128) out[b * ROI + c] = f[c] * inv;
  if (tid < NC) out[NB * ROI + b * NC + tid] = 0.5f * (probs[b * NC + tid] + probs[NB * NC + b * NC + tid]);
}

// ---------------------------------------------------------------- pooling
__global__ __launch_bounds__(128) void score_kernel(const float* __restrict__ M, const float* __restrict__ X,
                                                    const float* __restrict__ pws, const float* __restrict__ pwf,
                                                    const float* __restrict__ pmw, const float* __restrict__ pmb,
                                                    float* __restrict__ scores) {
  int i = blockIdx.x, b = blockIdx.y, tid = threadIdx.x;
  const float* mr = M + ((size_t)b * ROI + i) * ROI;
  const float* xr = X + ((size_t)b * ROI + i) * ROI;
  float s1 = 0.f, s2 = 0.f;
  for (int j = tid; j < ROI; j += 128) { s1 += mr[j] * pws[j]; s2 += xr[j] * pwf[j]; }
  __shared__ float r1[128], r2[128];
  r1[tid] = s1; r2[tid] = s2; __syncthreads();
  for (int st = 64; st > 0; st >>= 1) {
    if (tid < st) { r1[tid] += r1[tid + st]; r2[tid] += r2[tid + st]; }
    __syncthreads();
  }
  if (tid == 0) {
    float a = fabsf(r1[0]), c = fabsf(r2[0]);
    float z = a * pmw[0] + c * pmw[1] + pmb[0];
    scores[b * ROI + i] = 1.f / (1.f + expf(-z));
  }
}

__global__ __launch_bounds__(128) void select_kernel(const float* __restrict__ scores, int* __restrict__ idx) {
  int b = blockIdx.x, tid = threadIdx.x;
  __shared__ float sc[ROI];
  __shared__ int sel[ROI];
  for (int i = tid; i < ROI; i += 128) sc[i] = scores[b * ROI + i];
  __syncthreads();
  for (int i = tid; i < ROI; i += 128) {
    float si = sc[i];
    int rank = 0;
    for (int j = 0; j < ROI; ++j) {
      float sj = sc[j];
      rank += (sj > si) || (sj == si && j < i);
    }
    sel[i] = (rank < KPOOL) ? 1 : 0;
  }
  __syncthreads();
  for (int i = tid; i < ROI; i += 128) {
    if (sel[i]) {
      int pos = 0;
      for (int j = 0; j < i; ++j) pos += sel[j];
      idx[b * KPOOL + pos] = i;
    }
  }
}

__global__ __launch_bounds__(128) void gatherx_kernel(const float* __restrict__ X, const float* __restrict__ scores,
                                                      const int* __restrict__ idx, float* __restrict__ Xp,
                                                      unsigned short* __restrict__ XpH,
                                                      unsigned short* __restrict__ XpL) {
  int p = blockIdx.x % KPOOL, b = blockIdx.x / KPOOL, tid = threadIdx.x;
  int src = idx[b * KPOOL + p];
  float sw = scores[b * ROI + src];
  const float* xr = X + ((size_t)b * ROI + src) * ROI;
  size_t ro = ((size_t)b * KPOOL + p) * ROI;
  float* o = Xp + ro;
  for (int c = tid; c < ROI; c += 128) {
    float v = xr[c] * sw;
    o[c] = v;
    unsigned short hh, ll;
    split2(v, hh, ll);
    XpH[ro + c] = hh;
    XpL[ro + c] = ll;
  }
}

__global__ __launch_bounds__(128) void gatherm_kernel(const float* __restrict__ M, const int* __restrict__ idx,
                                                      float* __restrict__ Mp) {
  int p = blockIdx.x % KPOOL, b = blockIdx.x / KPOOL, tid = threadIdx.x;
  __shared__ int id[KPOOL];
  for (int q = tid; q < KPOOL; q += 128) id[q] = idx[b * KPOOL + q];
  __syncthreads();
  int src = idx[b * KPOOL + p];
  const float* mr = M + ((size_t)b * ROI + src) * ROI;
  float* o = Mp + ((size_t)b * KPOOL + p) * KPOOL;
  for (int q = tid; q < KPOOL; q += 128) o[q] = mr[id[q]];
}

// ---------------------------------------------------------------- host orchestration
template<int EPI>
static inline void mgemm(const unsigned short* AH, const unsigned short* AL,
                         const unsigned short* WH, const unsigned short* WL,
                         const float* bias, const float* res, int ldr,
                         float* C, unsigned short* CH, unsigned short* CL,
                         int M, int N, int K, hipStream_t st) {
  dim3 g((N + TBN - 1) / TBN, M / TBM);
  mgemm_kernel<EPI><<<g, 256, 0, st>>>(AH, AL, WH, WL, bias, res, ldr, C, CH, CL, M, N, K);
}

static inline void packa(const float* A, int lda, int M, int K, unsigned short* AH, unsigned short* AL,
                         hipStream_t st) {
  int total4 = M * K / 4;
  packa_kernel<<<(total4 + 255) / 256, 256, 0, st>>>(A, lda, K, total4, AH, AL);
}

static inline void pack_depth(const float* wq, const float* wk, const float* wv, const float* wo,
                              const float* w1, const float* w2,
                              unsigned short* qkvH, unsigned short* qkvL,
                              unsigned short* woH, unsigned short* woL,
                              unsigned short* w1H, unsigned short* w1L,
                              unsigned short* w2H, unsigned short* w2L, hipStream_t st) {
  PackAll pa;
  int blk = 0;
  auto add = [&](int i, const float* W, unsigned short* WH, unsigned short* WL, int K, int N) {
    int nbx = (N + 63) / 64, nby = (K + 63) / 64;
    pa.d[i] = {W, WH, WL, K, N, nbx, blk};
    blk += nbx * nby;
  };
  add(0, wq, qkvH + 0,      qkvL + 0,      ROI, ROI);
  add(1, wk, qkvH + 160000, qkvL + 160000, ROI, ROI);
  add(2, wv, qkvH + 320000, qkvL + 320000, ROI, ROI);
  add(3, wo, woH, woL, ROI, ROI);
  add(4, w1, w1H, w1L, ROI, HIDF);
  add(5, w2, w2H, w2L, HIDF, ROI);
  packall_kernel<<<blk, 256, 0, st>>>(pa);
}

extern "C" void kernel_launch(void* const* d_in, const int* in_sizes, int n_in,
                              void* d_out, int out_size, void* d_ws, size_t ws_size,
                              hipStream_t stream) {
  const float* in  = (const float*)d_in[0];
  const float* sel = (const float*)d_in[1];
  const float* wq  = (const float*)d_in[2];
  const float* wk  = (const float*)d_in[3];
  const float* wv  = (const float*)d_in[4];
  const float* wo  = (const float*)d_in[5];
  const float* bo  = (const float*)d_in[6];
  const float* w1  = (const float*)d_in[7];
  const float* b1  = (const float*)d_in[8];
  const float* w2  = (const float*)d_in[9];
  const float* b2  = (const float*)d_in[10];
  const float* lng = (const float*)d_in[11];
  const float* lnb = (const float*)d_in[12];
  const float* pws = (const float*)d_in[13];
  const float* pwf = (const float*)d_in[14];
  const float* pmw = (const float*)d_in[15];
  const float* pmb = (const float*)d_in[16];
  const float* r1w = (const float*)d_in[17];
  const float* r1b = (const float*)d_in[18];
  const float* r2w = (const float*)d_in[19];
  const float* r2b = (const float*)d_in[20];
  float* out = (float*)d_out;

  float* ws = (float*)d_ws;
  const size_t AT = (size_t)NB * ROI * ROI;  // 10,240,000 floats per slab

  unsigned short* up = (unsigned short*)ws;
  unsigned short* qkvH = up;                 // [1200][400]
  unsigned short* qkvL = up + 480000;
  unsigned short* woH  = up + 960000;        // [400][400]
  unsigned short* woL  = up + 1120000;
  unsigned short* w1H  = up + 1280000;       // [800][400]
  unsigned short* w1L  = up + 1600000;
  unsigned short* w2H  = up + 1920000;       // [400][800]
  unsigned short* w2L  = up + 2240000;       // ends 2.88M u16 < 1 slab

  float* smalls = ws + 6 * AT;
  float* meanb = smalls;
  float* stdb  = smalls + 64;
  float* scores = smalls + 128;
  int*   idx = (int*)(smalls + 128 + NB * ROI);
  float* probs = smalls + 128 + NB * ROI + NB * KPOOL;
  double* pp = (double*)(smalls + 128 + NB * ROI + NB * KPOOL + 2 * NB * NC + 16);

  float* Mmask = ws + AT;

  pre_partial_kernel<<<dim3(NB, CTT), 256, 0, stream>>>(in, pp);
  pre_final_kernel<<<1, 64, 0, stream>>>(pp, meanb, stdb);
  build_m_kernel<<<(int)((AT + 255) / 256), 256, 0, stream>>>(in, sel, meanb, stdb, Mmask);

  // ---------------- depth 0: N=400, Mtok=25600
  {
    const int N = ROI;
    const int Mtok = NB * N;  // 25600
    pack_depth(wq, wk, wv, wo, w1, w2, qkvH, qkvL, woH, woL, w1H, w1L, w2H, w2L, stream);

    unsigned short* AinH = (unsigned short*)(ws + 5 * AT);
    unsigned short* AinL = AinH + (size_t)Mtok * ROI;
    packa(in, 2 * ROI, Mtok, ROI, AinH, AinL, stream);

    unsigned short* QKVH_ = (unsigned short*)(ws + 2 * AT);          // [2AT,5AT)
    unsigned short* QKVL_ = QKVH_ + (size_t)Mtok * (3 * ROI);
    mgemm<6>(AinH, AinL, qkvH, qkvL, nullptr, nullptr, 0, nullptr, QKVH_, QKVL_,
             Mtok, 3 * ROI, ROI, stream);

    unsigned short* OpH = (unsigned short*)(ws + 5 * AT);            // over Ain planes (dead)
    unsigned short* OpL = OpH + (size_t)Mtok * ROI;
    fattn_kernel<<<dim3(NB * HEADS, (N + 63) / 64), 256, 0, stream>>>(
        QKVH_, QKVL_, Mmask, OpH, OpL, N);

    float* Xa0 = ws + 2 * AT;                                        // over QKV planes (dead)
    unsigned short* XaH = (unsigned short*)(ws + 3 * AT);
    unsigned short* XaL = XaH + (size_t)Mtok * ROI;
    mgemm<5>(OpH, OpL, woH, woL, bo, in, 2 * ROI, Xa0, XaH, XaL,
             Mtok, ROI, ROI, stream);

    unsigned short* Hh = (unsigned short*)(ws + 4 * AT);             // [4AT,5AT)
    unsigned short* Hl = (unsigned short*)(ws + 5 * AT);             // [5AT,6AT) — Op dead
    mgemm<4>(XaH, XaL, w1H, w1L, b1, nullptr, 0, nullptr, Hh, Hl,
             Mtok, HIDF, ROI, stream);

    float* Y0 = ws + 3 * AT;                                         // over Xa planes (dead)
    mgemm<2>(Hh, Hl, w2H, w2L, b2, Xa0, ROI, Y0, nullptr, nullptr,
             Mtok, ROI, HIDF, stream);

    float* Xn = ws + 2 * AT;                                         // over Xa0 (dead)
    ln_kernel<<<Mtok, 128, 0, stream>>>(Y0, lng, lnb, Xn);

    float* gfp0 = ws + 3 * AT;                                       // over Y0 (dead)
    colmean_kernel<<<dim3(NB, CTT), 128, 0, stream>>>(Xn, gfp0, N);
    head_kernel<<<NB, 128, 0, stream>>>(gfp0, r1w, r1b, r2w, r2b, probs, N);

    score_kernel<<<dim3(ROI, NB), 128, 0, stream>>>(Mmask, Xn, pws, pwf, pmw, pmb, scores);
    select_kernel<<<NB, 128, 0, stream>>>(scores, idx);
    float* Mp = ws + 4 * AT + 1200000;                               // over Hh (dead)
    gatherm_kernel<<<NB * KPOOL, 128, 0, stream>>>(Mmask, idx, Mp);  // Mmask last use
    float* Xp = ws + 5 * AT;                                         // over Hl (dead)
    unsigned short* XpH = (unsigned short*)(ws + AT);                // over Mmask (dead)
    unsigned short* XpL = XpH + (size_t)NB * KPOOL * ROI;
    gatherx_kernel<<<NB * KPOOL, 128, 0, stream>>>(Xn, scores, idx, Xp, XpH, XpL);
  }

  // ---------------- depth 1: N=280, Mtok=17920
  {
    const int N = KPOOL;
    const int Mtok = NB * N;  // 17920
    const int d = 1;
    const float* wq1 = wq + (size_t)d * ROI * ROI;
    const float* wk1 = wk + (size_t)d * ROI * ROI;
    const float* wv1 = wv + (size_t)d * ROI * ROI;
    const float* wo1 = wo + (size_t)d * ROI * ROI;
    const float* bo1 = bo + (size_t)d * ROI;
    const float* w11 = w1 + (size_t)d * ROI * HIDF;
    const float* b11 = b1 + (size_t)d * HIDF;
    const float* w21 = w2 + (size_t)d * HIDF * ROI;
    const float* b21 = b2 + (size_t)d * ROI;
    const float* lng1 = lng + (size_t)d * ROI;
    const float* lnb1 = lnb + (size_t)d * ROI;
    const float* r1w1 = r1w + (size_t)d * ROI * 128;
    const float* r1b1 = r1b + (size_t)d * 128;
    const float* r2w1 = r2w + (size_t)d * 128 * NC;
    const float* r2b1 = r2b + (size_t)d * NC;

    float* Xp = ws + 5 * AT;
    float* Mp = ws + 4 * AT + 1200000;
    unsigned short* XpH = (unsigned short*)(ws + AT);
    unsigned short* XpL = XpH + (size_t)Mtok * ROI;

    pack_depth(wq1, wk1, wv1, wo1, w11, w21, qkvH, qkvL, woH, woL, w1H, w1L, w2H, w2L, stream);

    unsigned short* QKVH_ = (unsigned short*)(ws + 2 * AT);          // ends before Mp
    unsigned short* QKVL_ = QKVH_ + (size_t)Mtok * (3 * ROI);
    mgemm<6>(XpH, XpL, qkvH, qkvL, nullptr, nullptr, 0, nullptr, QKVH_, QKVL_,
             Mtok, 3 * ROI, ROI, stream);

    unsigned short* OpH = (unsigned short*)(ws + AT);                // over Xp planes (dead)
    unsigned short* OpL = OpH + (size_t)Mtok * ROI;
    fattn_kernel<<<dim3(NB * HEADS, (N + 63) / 64), 256, 0, stream>>>(
        QKVH_, QKVL_, Mp, OpH, OpL, N);

    float* Xa1 = ws + 2 * AT;                                        // over QKV planes (dead)
    unsigned short* XaH = (unsigned short*)(ws + 3 * AT);
    unsigned short* XaL = XaH + (size_t)Mtok * ROI;
    mgemm<5>(OpH, OpL, woH, woL, bo1, Xp, ROI, Xa1, XaH, XaL,
             Mtok, ROI, ROI, stream);

    unsigned short* H1h = (unsigned short*)(ws + 4 * AT);            // Mp dead after fattn
    unsigned short* H1l = (unsigned short*)(ws + 5 * AT);            // Xp dead after Xa1
    mgemm<4>(XaH, XaL, w1H, w1L, b11, nullptr, 0, nullptr, H1h, H1l,
             Mtok, HIDF, ROI, stream);

    float* Y1 = ws + AT;                                             // over Op planes (dead)
    mgemm<2>(H1h, H1l, w2H, w2L, b21, Xa1, ROI, Y1, nullptr, nullptr,
             Mtok, ROI, HIDF, stream);

    float* Xf = ws + 3 * AT;                                         // over Xa planes (dead)
    ln_kernel<<<Mtok, 128, 0, stream>>>(Y1, lng1, lnb1, Xf);

    float* gfp1 = ws + 2 * AT;                                       // over Xa1 (dead)
    colmean_kernel<<<dim3(NB, CTT), 128, 0, stream>>>(Xf, gfp1, N);
    head_kernel<<<NB, 128, 0, stream>>>(gfp1, r1w1, r1b1, r2w1, r2b1, probs + NB * NC, N);
    finalize_kernel<<<NB, 128, 0, stream>>>(gfp1, probs, out, N);
  }
  (void)in_sizes; (void)n_in; (void)out_size; (void)ws_size;
}

// Round 13
// 1442.150 us; speedup vs baseline: 1.1591x; 1.0917x over previous
//
#include <hip/hip_runtime.h>
#include <math.h>

#define ROI 400
#define HEADS 4
#define DH 100
#define NB 64
#define HIDF 800
#define NC 2
#define KPOOL 280
#define ATT_SCALE 0.1f
#define CTT 10

typedef __attribute__((ext_vector_type(8))) short short8v;
typedef __attribute__((ext_vector_type(8))) unsigned short u16x8;
typedef __attribute__((ext_vector_type(4))) float f32x4;

union U8 { short8v v; unsigned short u[8]; };

__device__ __forceinline__ unsigned short f2bf(float x) {
  unsigned int u = __float_as_uint(x);
  u += 0x7fffu + ((u >> 16) & 1u);
  return (unsigned short)(u >> 16);
}
__device__ __forceinline__ void split2(float x, unsigned short& h, unsigned short& l) {
  h = f2bf(x);
  float hf = __uint_as_float(((unsigned int)h) << 16);
  l = f2bf(x - hf);
}

// ---------------------------------------------------------------- preprocess (two-stage)
__global__ __launch_bounds__(256) void pre_partial_kernel(const float* __restrict__ in,
                                                          double* __restrict__ pp) {
  int b = blockIdx.x, t = blockIdx.y;
  const float* p = in + (size_t)b * ROI * (2 * ROI);
  float s = 0.f, ss = 0.f;
  for (int e = threadIdx.x; e < 40 * ROI; e += 256) {
    int r = 40 * t + e / ROI, c = e % ROI;
    float v = log10f(p[(size_t)r * (2 * ROI) + ROI + c] + 1.0f);
    s += v; ss += v * v;
  }
  __shared__ double rs[256], rss[256];
  rs[threadIdx.x] = s; rss[threadIdx.x] = ss;
  __syncthreads();
  for (int st = 128; st > 0; st >>= 1) {
    if (threadIdx.x < st) { rs[threadIdx.x] += rs[threadIdx.x + st]; rss[threadIdx.x] += rss[threadIdx.x + st]; }
    __syncthreads();
  }
  if (threadIdx.x == 0) {
    pp[(b * CTT + t) * 2 + 0] = rs[0];
    pp[(b * CTT + t) * 2 + 1] = rss[0];
  }
}

__global__ __launch_bounds__(64) void pre_final_kernel(const double* __restrict__ pp,
                                                       float* __restrict__ meanb,
                                                       float* __restrict__ stdb) {
  int b = threadIdx.x;
  double s = 0.0, ss = 0.0;
  for (int t = 0; t < CTT; ++t) { s += pp[(b * CTT + t) * 2]; ss += pp[(b * CTT + t) * 2 + 1]; }
  const int n = ROI * ROI;
  double mean = s / n;
  double var = (ss - s * s / n) / (double)(n - 1);
  meanb[b] = (float)mean;
  stdb[b]  = (float)(sqrt(var) + 1e-6);
}

__global__ __launch_bounds__(256) void build_m_kernel(const float* __restrict__ in,
                                                      const float* __restrict__ sel,
                                                      const float* __restrict__ meanb,
                                                      const float* __restrict__ stdb,
                                                      float* __restrict__ M) {
  size_t e = (size_t)blockIdx.x * blockDim.x + threadIdx.x;
  const size_t total = (size_t)NB * ROI * ROI;
  if (e >= total) return;
  int c = (int)(e % ROI);
  int r = (int)((e / ROI) % ROI);
  int b = (int)(e / ((size_t)ROI * ROI));
  const float* row = in + ((size_t)b * ROI + r) * (2 * ROI);
  float v = log10f(row[ROI + c] + 1.0f);
  float sg = 1.0f / (1.0f + expf(-sel[r * ROI + c]));
  M[e] = ((v - meanb[b]) / stdb[b]) * sg;
}

// ---------------------------------------------------------------- batched weight pack (one launch / depth)
struct PackDesc {
  const float* W;
  unsigned short* WH;
  unsigned short* WL;
  int K, N, nbx, blk0;
};
struct PackAll { PackDesc d[6]; };

__global__ __launch_bounds__(256) void packall_kernel(PackAll pa) {
  int gb = blockIdx.x;
  int i = 0;
#pragma unroll
  for (int j = 1; j < 6; ++j) if (gb >= pa.d[j].blk0) i = j;
  const float* __restrict__ W = pa.d[i].W;
  unsigned short* __restrict__ WH = pa.d[i].WH;
  unsigned short* __restrict__ WL = pa.d[i].WL;
  const int K = pa.d[i].K, N = pa.d[i].N;
  int lb = gb - pa.d[i].blk0;
  int bn = (lb % pa.d[i].nbx) * 64;
  int bk = (lb / pa.d[i].nbx) * 64;

  __shared__ float t[64][68];
  int r = threadIdx.x >> 2;
  int c0 = (threadIdx.x & 3) << 4;
  int gk = bk + r;
#pragma unroll
  for (int q = 0; q < 4; ++q) {
    int c = c0 + 4 * q;
    float4 v = make_float4(0.f, 0.f, 0.f, 0.f);
    if (gk < K && bn + c < N) v = *(const float4*)(W + (size_t)gk * N + bn + c);
    *(float4*)&t[r][c] = v;
  }
  __syncthreads();
  int gn = bn + r;
#pragma unroll
  for (int q = 0; q < 4; ++q) {
    int c = c0 + 4 * q;
    int gkk = bk + c;
    if (gn < N && gkk < K) {
      ushort4 h, l;
      split2(t[c + 0][r], h.x, l.x);
      split2(t[c + 1][r], h.y, l.y);
      split2(t[c + 2][r], h.z, l.z);
      split2(t[c + 3][r], h.w, l.w);
      *(ushort4*)(WH + (size_t)gn * K + gkk) = h;
      *(ushort4*)(WL + (size_t)gn * K + gkk) = l;
    }
  }
}

// ---------------------------------------------------------------- activation pack
__global__ __launch_bounds__(256) void packa_kernel(const float* __restrict__ A, int lda, int K, int total4,
                                                    unsigned short* __restrict__ AH,
                                                    unsigned short* __restrict__ AL) {
  int e = blockIdx.x * 256 + threadIdx.x;
  if (e >= total4) return;
  int idx = e << 2;
  int row = idx / K, k = idx - row * K;
  float4 v = *(const float4*)(A + (size_t)row * lda + k);
  ushort4 h, l;
  split2(v.x, h.x, l.x); split2(v.y, h.y, l.y);
  split2(v.z, h.z, l.z); split2(v.w, h.w, l.w);
  *(ushort4*)(AH + (size_t)row * K + k) = h;
  *(ushort4*)(AL + (size_t)row * K + k) = l;
}

// ---------------------------------------------------------------- MFMA split-bf16 GEMM
// EPI: 0 plain float, 2 bias+res float, 4 bias+gelu -> split out, 5 bias+res -> float+split, 6 plain -> split out
#define TBM 128
#define TBN 128
#define TBK 32
#define KP 40

template<int EPI>
__global__ __launch_bounds__(256) void mgemm_kernel(const unsigned short* __restrict__ AHp,
                                                    const unsigned short* __restrict__ ALp,
                                                    const unsigned short* __restrict__ WH,
                                                    const unsigned short* __restrict__ WL,
                                                    const float* __restrict__ bias,
                                                    const float* __restrict__ res, int ldr,
                                                    float* __restrict__ C,
                                                    unsigned short* __restrict__ CH,
                                                    unsigned short* __restrict__ CL,
                                                    int M, int N, int K) {
  __shared__ unsigned short Ah[TBM][KP], Al[TBM][KP], Bh[TBN][KP], Bl[TBN][KP];
  const int tid = threadIdx.x;
  const int lane = tid & 63;
  const int wid = tid >> 6;
  const int wm = wid >> 1, wn = wid & 1;
  const int l15 = lane & 15, l4 = lane >> 4;
  const int bm = blockIdx.y * TBM;
  const int bn = blockIdx.x * TBN;

  f32x4 acc[4][4];
#pragma unroll
  for (int i = 0; i < 4; ++i)
#pragma unroll
    for (int j = 0; j < 4; ++j) acc[i][j] = (f32x4){0.f, 0.f, 0.f, 0.f};

  for (int k0 = 0; k0 < K; k0 += TBK) {
#pragma unroll
    for (int it = 0; it < 2; ++it) {
      int c = tid + 256 * it;
      int row = c >> 2;
      int kq = (c & 3) << 3;
      u16x8 vh = {0, 0, 0, 0, 0, 0, 0, 0};
      u16x8 vl = {0, 0, 0, 0, 0, 0, 0, 0};
      if (k0 + kq + 8 <= K) {
        size_t off = (size_t)(bm + row) * K + k0 + kq;
        vh = *(const u16x8*)(AHp + off);
        vl = *(const u16x8*)(ALp + off);
      }
      *(u16x8*)&Ah[row][kq] = vh;
      *(u16x8*)&Al[row][kq] = vl;
    }
#pragma unroll
    for (int it = 0; it < 2; ++it) {
      int c = tid + 256 * it;
      int row = c >> 2;
      int kq = (c & 3) << 3;
      int gn = bn + row;
      u16x8 vh = {0, 0, 0, 0, 0, 0, 0, 0};
      u16x8 vl = {0, 0, 0, 0, 0, 0, 0, 0};
      if (gn < N && k0 + kq + 8 <= K) {
        size_t off = (size_t)gn * K + k0 + kq;
        vh = *(const u16x8*)(WH + off);
        vl = *(const u16x8*)(WL + off);
      }
      *(u16x8*)&Bh[row][kq] = vh;
      *(u16x8*)&Bl[row][kq] = vl;
    }
    __syncthreads();

    short8v ah[4], alo[4], bh[4], blo[4];
#pragma unroll
    for (int mf = 0; mf < 4; ++mf) {
      int r = wm * 64 + mf * 16 + l15;
      ah[mf]  = *(const short8v*)&Ah[r][l4 * 8];
      alo[mf] = *(const short8v*)&Al[r][l4 * 8];
    }
#pragma unroll
    for (int nf = 0; nf < 4; ++nf) {
      int r = wn * 64 + nf * 16 + l15;
      bh[nf]  = *(const short8v*)&Bh[r][l4 * 8];
      blo[nf] = *(const short8v*)&Bl[r][l4 * 8];
    }
#pragma unroll
    for (int mf = 0; mf < 4; ++mf)
#pragma unroll
      for (int nf = 0; nf < 4; ++nf) {
        acc[mf][nf] = __builtin_amdgcn_mfma_f32_16x16x32_bf16(ah[mf], bh[nf], acc[mf][nf], 0, 0, 0);
        acc[mf][nf] = __builtin_amdgcn_mfma_f32_16x16x32_bf16(ah[mf], blo[nf], acc[mf][nf], 0, 0, 0);
        acc[mf][nf] = __builtin_amdgcn_mfma_f32_16x16x32_bf16(alo[mf], bh[nf], acc[mf][nf], 0, 0, 0);
      }
    __syncthreads();
  }

#pragma unroll
  for (int mf = 0; mf < 4; ++mf) {
#pragma unroll
    for (int nf = 0; nf < 4; ++nf) {
      int col = bn + wn * 64 + nf * 16 + l15;
      if (col < N) {
        float bv = (EPI >= 1 && EPI != 6) ? bias[col] : 0.f;
        int row0 = bm + wm * 64 + mf * 16 + l4 * 4;
#pragma unroll
        for (int r = 0; r < 4; ++r) {
          float v = acc[mf][nf][r] + bv;
          int row = row0 + r;
          if (EPI == 2 || EPI == 5) v += res[(size_t)row * ldr + col];
          if (EPI == 4) {
            v = 0.5f * v * (1.0f + erff(v * 0.70710678118654752f));
            unsigned short hh, ll;
            split2(v, hh, ll);
            CH[(size_t)row * N + col] = hh;
            CL[(size_t)row * N + col] = ll;
          } else if (EPI == 5) {
            C[(size_t)row * N + col] = v;
            unsigned short hh, ll;
            split2(v, hh, ll);
            CH[(size_t)row * N + col] = hh;
            CL[(size_t)row * N + col] = ll;
          } else if (EPI == 6) {
            unsigned short hh, ll;
            split2(v, hh, ll);
            CH[(size_t)row * N + col] = hh;
            CL[(size_t)row * N + col] = ll;
          } else {
            C[(size_t)row * N + col] = v;
          }
        }
      }
    }
  }
}

// ---------------------------------------------------------------- MFMA flash attention
// grid.x = h*NB + b: same-b blocks (all 4 heads, sharing M[b]) at x-stride 64 ≡ 0 mod 8 -> same XCD;
// i-blocks of same (b,h) at linear stride 256 ≡ 0 mod 8 -> same XCD. M becomes L2-resident.
// Register double-buffer (T14): next tile's K/V/M loads issue before current tile's compute.
#define FBJ 32

__global__ __launch_bounds__(256) void fattn_kernel(const unsigned short* __restrict__ QKVH,
                                                    const unsigned short* __restrict__ QKVL,
                                                    const float* __restrict__ Mm,
                                                    unsigned short* __restrict__ OH,
                                                    unsigned short* __restrict__ OL, int N) {
  const int ldq = 3 * ROI;
  __shared__ unsigned short Kh[FBJ][136], Kl[FBJ][136];
  __shared__ unsigned short Vth[112][40], Vtl[112][40];
  __shared__ unsigned short Ph[64][40], Pl[64][40];

  const int tid = threadIdx.x;
  const int lane = tid & 63;
  const int w = tid >> 6;
  const int l15 = lane & 15, l4 = lane >> 4;
  const int b = blockIdx.x & (NB - 1);
  const int h = blockIdx.x >> 6;
  const int i0 = blockIdx.y * 64;

  const float* Mb = Mm + (size_t)b * N * N;

  for (int e = tid; e < 12 * 40; e += 256) {
    Vth[100 + e / 40][e % 40] = 0; Vtl[100 + e / 40][e % 40] = 0;
  }

  // Q fragments straight from split planes
  int qr = i0 + 16 * w + l15; if (qr >= N) qr = N - 1;
  const unsigned short* qrH = QKVH + ((size_t)b * N + qr) * ldq + h * DH;
  const unsigned short* qrL = QKVL + ((size_t)b * N + qr) * ldq + h * DH;
  short8v qh[4], ql[4];
#pragma unroll
  for (int kg = 0; kg < 4; ++kg) {
    int d0v = kg * 32 + l4 * 8;
    U8 th, tl;
    if (d0v + 8 <= DH) {
      *(ushort4*)&th.u[0] = *(const ushort4*)(qrH + d0v);
      *(ushort4*)&th.u[4] = *(const ushort4*)(qrH + d0v + 4);
      *(ushort4*)&tl.u[0] = *(const ushort4*)(qrL + d0v);
      *(ushort4*)&tl.u[4] = *(const ushort4*)(qrL + d0v + 4);
    } else if (d0v < DH) {
      *(ushort4*)&th.u[0] = *(const ushort4*)(qrH + d0v);
      *(ushort4*)&tl.u[0] = *(const ushort4*)(qrL + d0v);
#pragma unroll
      for (int j = 4; j < 8; ++j) { th.u[j] = 0; tl.u[j] = 0; }
    } else {
#pragma unroll
      for (int j = 0; j < 8; ++j) { th.u[j] = 0; tl.u[j] = 0; }
    }
    qh[kg] = th.v; ql[kg] = tl.v;
  }

  // ---- prefetch registers (double buffer)
  ushort4 kHp[4], kLp[4];
  ushort4 vAH[2], vBH[2], vAL[2], vBL[2];
  float mnext[4][2];

  // prologue: load tile 0
  {
    const int j0 = 0;
#pragma unroll
    for (int it = 0; it < 4; ++it) {
      int e = tid + 256 * it;
      int kv = e >> 5, dq = (e & 31) << 2;
      int gj = j0 + kv; if (gj >= N) gj = N - 1;
      ushort4 hh = {0, 0, 0, 0}, ll = {0, 0, 0, 0};
      if (dq < DH) {
        size_t off = ((size_t)b * N + gj) * ldq + ROI + h * DH + dq;
        hh = *(const ushort4*)(QKVH + off); ll = *(const ushort4*)(QKVL + off);
      }
      kHp[it] = hh; kLp[it] = ll;
    }
#pragma unroll
    for (int it = 0; it < 2; ++it) {
      int e = tid + 256 * it;
      ushort4 z = {0, 0, 0, 0};
      vAH[it] = z; vBH[it] = z; vAL[it] = z; vBL[it] = z;
      if (e < 400) {
        int kvp = e & 15, dq = (e >> 4) << 2;
        int gj0 = j0 + 2 * kvp;     if (gj0 >= N) gj0 = N - 1;
        int gj1 = j0 + 2 * kvp + 1; if (gj1 >= N) gj1 = N - 1;
        size_t o0 = ((size_t)b * N + gj0) * ldq + 2 * ROI + h * DH + dq;
        size_t o1 = ((size_t)b * N + gj1) * ldq + 2 * ROI + h * DH + dq;
        vAH[it] = *(const ushort4*)(QKVH + o0);
        vBH[it] = *(const ushort4*)(QKVH + o1);
        vAL[it] = *(const ushort4*)(QKVL + o0);
        vBL[it] = *(const ushort4*)(QKVL + o1);
      }
    }
#pragma unroll
    for (int r = 0; r < 4; ++r) {
      int gq = i0 + 16 * w + l4 * 4 + r;
      int gqc = (gq < N) ? gq : N - 1;
      const float* Mr = Mb + (size_t)gqc * N;
      int kv0 = j0 + l15, kv1 = j0 + l15 + 16;
      mnext[r][0] = (kv0 < N) ? Mr[kv0] : 0.f;
      mnext[r][1] = (kv1 < N) ? Mr[kv1] : 0.f;
    }
  }

  float m_i[4], l_i[4];
  f32x4 o[7];
#pragma unroll
  for (int r = 0; r < 4; ++r) { m_i[r] = -INFINITY; l_i[r] = 0.f; }
#pragma unroll
  for (int ff = 0; ff < 7; ++ff) o[ff] = (f32x4){0.f, 0.f, 0.f, 0.f};

  const int njt = (N + FBJ - 1) / FBJ;
  for (int jt = 0; jt < njt; ++jt) {
    const int j0 = jt * FBJ;
    const int kv0 = j0 + l15, kv1 = j0 + l15 + 16;

    __syncthreads();   // prev PV done reading LDS
    // store prefetched regs -> LDS
#pragma unroll
    for (int it = 0; it < 4; ++it) {
      int e = tid + 256 * it;
      int kv = e >> 5, dq = (e & 31) << 2;
      *(ushort4*)&Kh[kv][dq] = kHp[it];
      *(ushort4*)&Kl[kv][dq] = kLp[it];
    }
#pragma unroll
    for (int it = 0; it < 2; ++it) {
      int e = tid + 256 * it;
      if (e < 400) {
        int kvp = e & 15, dq = (e >> 4) << 2;
        *(unsigned int*)&Vth[dq + 0][2 * kvp] = (unsigned int)vAH[it].x | ((unsigned int)vBH[it].x << 16);
        *(unsigned int*)&Vth[dq + 1][2 * kvp] = (unsigned int)vAH[it].y | ((unsigned int)vBH[it].y << 16);
        *(unsigned int*)&Vth[dq + 2][2 * kvp] = (unsigned int)vAH[it].z | ((unsigned int)vBH[it].z << 16);
        *(unsigned int*)&Vth[dq + 3][2 * kvp] = (unsigned int)vAH[it].w | ((unsigned int)vBH[it].w << 16);
        *(unsigned int*)&Vtl[dq + 0][2 * kvp] = (unsigned int)vAL[it].x | ((unsigned int)vBL[it].x << 16);
        *(unsigned int*)&Vtl[dq + 1][2 * kvp] = (unsigned int)vAL[it].y | ((unsigned int)vBL[it].y << 16);
        *(unsigned int*)&Vtl[dq + 2][2 * kvp] = (unsigned int)vAL[it].z | ((unsigned int)vBL[it].z << 16);
        *(unsigned int*)&Vtl[dq + 3][2 * kvp] = (unsigned int)vAL[it].w | ((unsigned int)vBL[it].w << 16);
      }
    }
    float mcur[4][2];
#pragma unroll
    for (int r = 0; r < 4; ++r) { mcur[r][0] = mnext[r][0]; mcur[r][1] = mnext[r][1]; }
    __syncthreads();   // LDS ready

    // issue next tile's loads (latency hidden under QK^T + softmax + PV)
    if (jt + 1 < njt) {
      const int jn = j0 + FBJ;
#pragma unroll
      for (int it = 0; it < 4; ++it) {
        int e = tid + 256 * it;
        int kv = e >> 5, dq = (e & 31) << 2;
        int gj = jn + kv; if (gj >= N) gj = N - 1;
        ushort4 hh = {0, 0, 0, 0}, ll = {0, 0, 0, 0};
        if (dq < DH) {
          size_t off = ((size_t)b * N + gj) * ldq + ROI + h * DH + dq;
          hh = *(const ushort4*)(QKVH + off); ll = *(const ushort4*)(QKVL + off);
        }
        kHp[it] = hh; kLp[it] = ll;
      }
#pragma unroll
      for (int it = 0; it < 2; ++it) {
        int e = tid + 256 * it;
        if (e < 400) {
          int kvp = e & 15, dq = (e >> 4) << 2;
          int gj0 = jn + 2 * kvp;     if (gj0 >= N) gj0 = N - 1;
          int gj1 = jn + 2 * kvp + 1; if (gj1 >= N) gj1 = N - 1;
          size_t o0 = ((size_t)b * N + gj0) * ldq + 2 * ROI + h * DH + dq;
          size_t o1 = ((size_t)b * N + gj1) * ldq + 2 * ROI + h * DH + dq;
          vAH[it] = *(const ushort4*)(QKVH + o0);
          vBH[it] = *(const ushort4*)(QKVH + o1);
          vAL[it] = *(const ushort4*)(QKVL + o0);
          vBL[it] = *(const ushort4*)(QKVL + o1);
        }
      }
#pragma unroll
      for (int r = 0; r < 4; ++r) {
        int gq = i0 + 16 * w + l4 * 4 + r;
        int gqc = (gq < N) ? gq : N - 1;
        const float* Mr = Mb + (size_t)gqc * N;
        int nkv0 = jn + l15, nkv1 = jn + l15 + 16;
        mnext[r][0] = (nkv0 < N) ? Mr[nkv0] : 0.f;
        mnext[r][1] = (nkv1 < N) ? Mr[nkv1] : 0.f;
      }
    }

    // QK^T
    f32x4 sacc[2];
    sacc[0] = (f32x4){0.f, 0.f, 0.f, 0.f};
    sacc[1] = (f32x4){0.f, 0.f, 0.f, 0.f};
    __builtin_amdgcn_s_setprio(1);
#pragma unroll
    for (int kg = 0; kg < 4; ++kg) {
#pragma unroll
      for (int f = 0; f < 2; ++f) {
        short8v bh = *(const short8v*)&Kh[l15 + 16 * f][kg * 32 + l4 * 8];
        short8v bl = *(const short8v*)&Kl[l15 + 16 * f][kg * 32 + l4 * 8];
        sacc[f] = __builtin_amdgcn_mfma_f32_16x16x32_bf16(qh[kg], bh, sacc[f], 0, 0, 0);
        sacc[f] = __builtin_amdgcn_mfma_f32_16x16x32_bf16(qh[kg], bl, sacc[f], 0, 0, 0);
        sacc[f] = __builtin_amdgcn_mfma_f32_16x16x32_bf16(ql[kg], bh, sacc[f], 0, 0, 0);
      }
    }
    __builtin_amdgcn_s_setprio(0);

    // softmax using mcur
#pragma unroll
    for (int r = 0; r < 4; ++r) {
      float s0 = (kv0 < N) ? sacc[0][r] * ATT_SCALE * (1.0f + mcur[r][0]) : -INFINITY;
      float s1 = (kv1 < N) ? sacc[1][r] * ATT_SCALE * (1.0f + mcur[r][1]) : -INFINITY;
      float rm = fmaxf(s0, s1);
      rm = fmaxf(rm, __shfl_xor(rm, 1, 16));
      rm = fmaxf(rm, __shfl_xor(rm, 2, 16));
      rm = fmaxf(rm, __shfl_xor(rm, 4, 16));
      rm = fmaxf(rm, __shfl_xor(rm, 8, 16));
      float nm = fmaxf(m_i[r], rm);
      float fr = expf(m_i[r] - nm);
      float p0 = (kv0 < N) ? expf(s0 - nm) : 0.f;
      float p1 = (kv1 < N) ? expf(s1 - nm) : 0.f;
      float ts = p0 + p1;
      ts += __shfl_xor(ts, 1, 16);
      ts += __shfl_xor(ts, 2, 16);
      ts += __shfl_xor(ts, 4, 16);
      ts += __shfl_xor(ts, 8, 16);
      l_i[r] = l_i[r] * fr + ts;
      m_i[r] = nm;
#pragma unroll
      for (int ff = 0; ff < 7; ++ff) o[ff][r] *= fr;
      unsigned short h0, l0, h1, l1;
      split2(p0, h0, l0); split2(p1, h1, l1);
      int prow = 16 * w + l4 * 4 + r;
      Ph[prow][l15] = h0;      Pl[prow][l15] = l0;
      Ph[prow][l15 + 16] = h1; Pl[prow][l15 + 16] = l1;
    }
    __syncthreads();

    short8v ph = *(const short8v*)&Ph[16 * w + l15][l4 * 8];
    short8v pl = *(const short8v*)&Pl[16 * w + l15][l4 * 8];
    __builtin_amdgcn_s_setprio(1);
#pragma unroll
    for (int ff = 0; ff < 7; ++ff) {
      short8v vh = *(const short8v*)&Vth[ff * 16 + l15][l4 * 8];
      short8v vl = *(const short8v*)&Vtl[ff * 16 + l15][l4 * 8];
      o[ff] = __builtin_amdgcn_mfma_f32_16x16x32_bf16(ph, vh, o[ff], 0, 0, 0);
      o[ff] = __builtin_amdgcn_mfma_f32_16x16x32_bf16(ph, vl, o[ff], 0, 0, 0);
      o[ff] = __builtin_amdgcn_mfma_f32_16x16x32_bf16(pl, vh, o[ff], 0, 0, 0);
    }
    __builtin_amdgcn_s_setprio(0);
  }

#pragma unroll
  for (int r = 0; r < 4; ++r) {
    int gq = i0 + 16 * w + l4 * 4 + r;
    if (gq < N) {
      float inv = 1.0f / l_i[r];
      size_t rowoff = ((size_t)b * N + gq) * ROI + h * DH;
#pragma unroll
      for (int ff = 0; ff < 7; ++ff) {
        int d = ff * 16 + l15;
        if (d < DH) {
          unsigned short hh, ll;
          split2(o[ff][r] * inv, hh, ll);
          OH[rowoff + d] = hh;
          OL[rowoff + d] = ll;
        }
      }
    }
  }
}

// ---------------------------------------------------------------- layernorm
__global__ __launch_bounds__(128) void ln_kernel(const float* __restrict__ Y, const float* __restrict__ g,
                                                 const float* __restrict__ bta, float* __restrict__ X) {
  int row = blockIdx.x;
  const float* y = Y + (size_t)row * ROI;
  float* x = X + (size_t)row * ROI;
  int tid = threadIdx.x;
  __shared__ float red[128];
  float s = 0.f;
  for (int c = tid; c < ROI; c += 128) s += y[c];
  red[tid] = s; __syncthreads();
  for (int st = 64; st > 0; st >>= 1) { if (tid < st) red[tid] += red[tid + st]; __syncthreads(); }
  float mu = red[0] / ROI;
  __syncthreads();
  float v = 0.f;
  for (int c = tid; c < ROI; c += 128) { float d = y[c] - mu; v += d * d; }
  red[tid] = v; __syncthreads();
  for (int st = 64; st > 0; st >>= 1) { if (tid < st) red[tid] += red[tid + st]; __syncthreads(); }
  float rstd = rsqrtf(red[0] / ROI + 1e-5f);
  for (int c = tid; c < ROI; c += 128) x[c] = (y[c] - mu) * rstd * g[c] + bta[c];
}

// ---------------------------------------------------------------- column-mean partials
__global__ __launch_bounds__(128) void colmean_kernel(const float* __restrict__ X,
                                                      float* __restrict__ gfp, int N) {
  int b = blockIdx.x, t = blockIdx.y, tid = threadIdx.x;
  int per = (N + CTT - 1) / CTT;
  int n0 = t * per, n1 = n0 + per;
  if (n1 > N) n1 = N;
  float a0 = 0.f, a1 = 0.f, a2 = 0.f, a3 = 0.f;
  for (int n = n0; n < n1; ++n) {
    const float* row = X + ((size_t)b * N + n) * ROI;
    a0 += row[tid]; a1 += row[tid + 128]; a2 += row[tid + 256];
    if (tid < 16) a3 += row[tid + 384];
  }
  float* g = gfp + ((size_t)b * CTT + t) * ROI;
  g[tid] = a0; g[tid + 128] = a1; g[tid + 256] = a2;
  if (tid < 16) g[tid + 384] = a3;
}

// ---------------------------------------------------------------- classifier head (from partials)
__global__ __launch_bounds__(128) void head_kernel(const float* __restrict__ gfp,
                                                   const float* __restrict__ r1w, const float* __restrict__ r1b,
                                                   const float* __restrict__ r2w, const float* __restrict__ r2b,
                                                   float* __restrict__ probs, int N) {
  int b = blockIdx.x, tid = threadIdx.x;
  __shared__ float gf[ROI];
  __shared__ float hid[128];
  for (int c = tid; c < ROI; c += 128) {
    float s = 0.f;
    for (int t = 0; t < CTT; ++t) s += gfp[((size_t)b * CTT + t) * ROI + c];
    gf[c] = s / (float)N;
  }
  __syncthreads();
  {
    float a = r1b[tid];
    for (int k = 0; k < ROI; ++k) a += gf[k] * r1w[k * 128 + tid];
    hid[tid] = (a >= 0.f) ? a : 0.01f * a;
  }
  __syncthreads();
  if (tid < NC) {
    float l = r2b[tid];
    for (int k = 0; k < 128; ++k) l += hid[k] * r2w[k * NC + tid];
    gf[tid] = l;
  }
  __syncthreads();
  if (tid == 0) {
    float m = fmaxf(gf[0], gf[1]);
    float e0 = expf(gf[0] - m), e1 = expf(gf[1] - m);
    float inv = 1.f / (e0 + e1);
    probs[b * NC + 0] = e0 * inv;
    probs[b * NC + 1] = e1 * inv;
  }
}

// ---------------------------------------------------------------- final output (from partials)
__global__ __launch_bounds__(128) void finalize_kernel(const float* __restrict__ gfp,
                                                       const float* __restrict__ probs,
                                                       float* __restrict__ out, int N) {
  int b = blockIdx.x, tid = threadIdx.x;
  __shared__ float f[ROI];
  __shared__ float red[128];
  for (int c = tid; c < ROI; c += 128) {
    float s = 0.f;
    for (int t = 0; t < CTT; ++t) s += gfp[((size_t)b * CTT + t) * ROI + c];
    f[c] = s / (float)N;
  }
  __syncthreads();
  float ls = 0.f;
  for (int c = tid; c < ROI; c += 128) ls += f[c] * f[c];
  red[tid] = ls; __syncthreads();
  for (int st = 64; st > 0; st >>= 1) { if (tid < st) red[tid] += red[tid + st]; __syncthreads(); }
  float inv = 1.f / fmaxf(sqrtf(red[0]), 1e-12f);
  for (int c = tid; c < ROI; c += 128) out[b * ROI + c] = f[c] * inv;
  if (tid < NC) out[NB * ROI + b * NC + tid] = 0.5f * (probs[b * NC + tid] + probs[NB * NC + b * NC + tid]);
}

// ---------------------------------------------------------------- pooling
__global__ __launch_bounds__(128) void score_kernel(const float* __restrict__ M, const float* __restrict__ X,
                                                    const float* __restrict__ pws, const float* __restrict__ pwf,
                                                    const float* __restrict__ pmw, const float* __restrict__ pmb,
                                                    float* __restrict__ scores) {
  int i = blockIdx.x, b = blockIdx.y, tid = threadIdx.x;
  const float* mr = M + ((size_t)b * ROI + i) * ROI;
  const float* xr = X + ((size_t)b * ROI + i) * ROI;
  float s1 = 0.f, s2 = 0.f;
  for (int j = tid; j < ROI; j += 128) { s1 += mr[j] * pws[j]; s2 += xr[j] * pwf[j]; }
  __shared__ float r1[128], r2[128];
  r1[tid] = s1; r2[tid] = s2; __syncthreads();
  for (int st = 64; st > 0; st >>= 1) {
    if (tid < st) { r1[tid] += r1[tid + st]; r2[tid] += r2[tid + st]; }
    __syncthreads();
  }
  if (tid == 0) {
    float a = fabsf(r1[0]), c = fabsf(r2[0]);
    float z = a * pmw[0] + c * pmw[1] + pmb[0];
    scores[b * ROI + i] = 1.f / (1.f + expf(-z));
  }
}

__global__ __launch_bounds__(128) void select_kernel(const float* __restrict__ scores, int* __restrict__ idx) {
  int b = blockIdx.x, tid = threadIdx.x;
  __shared__ float sc[ROI];
  __shared__ int sel[ROI];
  for (int i = tid; i < ROI; i += 128) sc[i] = scores[b * ROI + i];
  __syncthreads();
  for (int i = tid; i < ROI; i += 128) {
    float si = sc[i];
    int rank = 0;
    for (int j = 0; j < ROI; ++j) {
      float sj = sc[j];
      rank += (sj > si) || (sj == si && j < i);
    }
    sel[i] = (rank < KPOOL) ? 1 : 0;
  }
  __syncthreads();
  for (int i = tid; i < ROI; i += 128) {
    if (sel[i]) {
      int pos = 0;
      for (int j = 0; j < i; ++j) pos += sel[j];
      idx[b * KPOOL + pos] = i;
    }
  }
}

__global__ __launch_bounds__(128) void gatherx_kernel(const float* __restrict__ X, const float* __restrict__ scores,
                                                      const int* __restrict__ idx, float* __restrict__ Xp,
                                                      unsigned short* __restrict__ XpH,
                                                      unsigned short* __restrict__ XpL) {
  int p = blockIdx.x % KPOOL, b = blockIdx.x / KPOOL, tid = threadIdx.x;
  int src = idx[b * KPOOL + p];
  float sw = scores[b * ROI + src];
  const float* xr = X + ((size_t)b * ROI + src) * ROI;
  size_t ro = ((size_t)b * KPOOL + p) * ROI;
  float* o = Xp + ro;
  for (int c = tid; c < ROI; c += 128) {
    float v = xr[c] * sw;
    o[c] = v;
    unsigned short hh, ll;
    split2(v, hh, ll);
    XpH[ro + c] = hh;
    XpL[ro + c] = ll;
  }
}

__global__ __launch_bounds__(128) void gatherm_kernel(const float* __restrict__ M, const int* __restrict__ idx,
                                                      float* __restrict__ Mp) {
  int p = blockIdx.x % KPOOL, b = blockIdx.x / KPOOL, tid = threadIdx.x;
  __shared__ int id[KPOOL];
  for (int q = tid; q < KPOOL; q += 128) id[q] = idx[b * KPOOL + q];
  __syncthreads();
  int src = idx[b * KPOOL + p];
  const float* mr = M + ((size_t)b * ROI + src) * ROI;
  float* o = Mp + ((size_t)b * KPOOL + p) * KPOOL;
  for (int q = tid; q < KPOOL; q += 128) o[q] = mr[id[q]];
}

// ---------------------------------------------------------------- host orchestration
template<int EPI>
static inline void mgemm(const unsigned short* AH, const unsigned short* AL,
                         const unsigned short* WH, const unsigned short* WL,
                         const float* bias, const float* res, int ldr,
                         float* C, unsigned short* CH, unsigned short* CL,
                         int M, int N, int K, hipStream_t st) {
  dim3 g((N + TBN - 1) / TBN, M / TBM);
  mgemm_kernel<EPI><<<g, 256, 0, st>>>(AH, AL, WH, WL, bias, res, ldr, C, CH, CL, M, N, K);
}

static inline void packa(const float* A, int lda, int M, int K, unsigned short* AH, unsigned short* AL,
                         hipStream_t st) {
  int total4 = M * K / 4;
  packa_kernel<<<(total4 + 255) / 256, 256, 0, st>>>(A, lda, K, total4, AH, AL);
}

static inline void pack_depth(const float* wq, const float* wk, const float* wv, const float* wo,
                              const float* w1, const float* w2,
                              unsigned short* qkvH, unsigned short* qkvL,
                              unsigned short* woH, unsigned short* woL,
                              unsigned short* w1H, unsigned short* w1L,
                              unsigned short* w2H, unsigned short* w2L, hipStream_t st) {
  PackAll pa;
  int blk = 0;
  auto add = [&](int i, const float* W, unsigned short* WH, unsigned short* WL, int K, int N) {
    int nbx = (N + 63) / 64, nby = (K + 63) / 64;
    pa.d[i] = {W, WH, WL, K, N, nbx, blk};
    blk += nbx * nby;
  };
  add(0, wq, qkvH + 0,      qkvL + 0,      ROI, ROI);
  add(1, wk, qkvH + 160000, qkvL + 160000, ROI, ROI);
  add(2, wv, qkvH + 320000, qkvL + 320000, ROI, ROI);
  add(3, wo, woH, woL, ROI, ROI);
  add(4, w1, w1H, w1L, ROI, HIDF);
  add(5, w2, w2H, w2L, HIDF, ROI);
  packall_kernel<<<blk, 256, 0, st>>>(pa);
}

extern "C" void kernel_launch(void* const* d_in, const int* in_sizes, int n_in,
                              void* d_out, int out_size, void* d_ws, size_t ws_size,
                              hipStream_t stream) {
  const float* in  = (const float*)d_in[0];
  const float* sel = (const float*)d_in[1];
  const float* wq  = (const float*)d_in[2];
  const float* wk  = (const float*)d_in[3];
  const float* wv  = (const float*)d_in[4];
  const float* wo  = (const float*)d_in[5];
  const float* bo  = (const float*)d_in[6];
  const float* w1  = (const float*)d_in[7];
  const float* b1  = (const float*)d_in[8];
  const float* w2  = (const float*)d_in[9];
  const float* b2  = (const float*)d_in[10];
  const float* lng = (const float*)d_in[11];
  const float* lnb = (const float*)d_in[12];
  const float* pws = (const float*)d_in[13];
  const float* pwf = (const float*)d_in[14];
  const float* pmw = (const float*)d_in[15];
  const float* pmb = (const float*)d_in[16];
  const float* r1w = (const float*)d_in[17];
  const float* r1b = (const float*)d_in[18];
  const float* r2w = (const float*)d_in[19];
  const float* r2b = (const float*)d_in[20];
  float* out = (float*)d_out;

  float* ws = (float*)d_ws;
  const size_t AT = (size_t)NB * ROI * ROI;  // 10,240,000 floats per slab

  unsigned short* up = (unsigned short*)ws;
  unsigned short* qkvH = up;                 // [1200][400]
  unsigned short* qkvL = up + 480000;
  unsigned short* woH  = up + 960000;        // [400][400]
  unsigned short* woL  = up + 1120000;
  unsigned short* w1H  = up + 1280000;       // [800][400]
  unsigned short* w1L  = up + 1600000;
  unsigned short* w2H  = up + 1920000;       // [400][800]
  unsigned short* w2L  = up + 2240000;       // ends 2.88M u16 < 1 slab

  float* smalls = ws + 6 * AT;
  float* meanb = smalls;
  float* stdb  = smalls + 64;
  float* scores = smalls + 128;
  int*   idx = (int*)(smalls + 128 + NB * ROI);
  float* probs = smalls + 128 + NB * ROI + NB * KPOOL;
  double* pp = (double*)(smalls + 128 + NB * ROI + NB * KPOOL + 2 * NB * NC + 16);

  float* Mmask = ws + AT;

  pre_partial_kernel<<<dim3(NB, CTT), 256, 0, stream>>>(in, pp);
  pre_final_kernel<<<1, 64, 0, stream>>>(pp, meanb, stdb);
  build_m_kernel<<<(int)((AT + 255) / 256), 256, 0, stream>>>(in, sel, meanb, stdb, Mmask);

  // ---------------- depth 0: N=400, Mtok=25600
  {
    const int N = ROI;
    const int Mtok = NB * N;  // 25600
    pack_depth(wq, wk, wv, wo, w1, w2, qkvH, qkvL, woH, woL, w1H, w1L, w2H, w2L, stream);

    unsigned short* AinH = (unsigned short*)(ws + 5 * AT);
    unsigned short* AinL = AinH + (size_t)Mtok * ROI;
    packa(in, 2 * ROI, Mtok, ROI, AinH, AinL, stream);

    unsigned short* QKVH_ = (unsigned short*)(ws + 2 * AT);          // [2AT,5AT)
    unsigned short* QKVL_ = QKVH_ + (size_t)Mtok * (3 * ROI);
    mgemm<6>(AinH, AinL, qkvH, qkvL, nullptr, nullptr, 0, nullptr, QKVH_, QKVL_,
             Mtok, 3 * ROI, ROI, stream);

    unsigned short* OpH = (unsigned short*)(ws + 5 * AT);            // over Ain planes (dead)
    unsigned short* OpL = OpH + (size_t)Mtok * ROI;
    fattn_kernel<<<dim3(HEADS * NB, (N + 63) / 64), 256, 0, stream>>>(
        QKVH_, QKVL_, Mmask, OpH, OpL, N);

    float* Xa0 = ws + 2 * AT;                                        // over QKV planes (dead)
    unsigned short* XaH = (unsigned short*)(ws + 3 * AT);
    unsigned short* XaL = XaH + (size_t)Mtok * ROI;
    mgemm<5>(OpH, OpL, woH, woL, bo, in, 2 * ROI, Xa0, XaH, XaL,
             Mtok, ROI, ROI, stream);

    unsigned short* Hh = (unsigned short*)(ws + 4 * AT);             // [4AT,5AT)
    unsigned short* Hl = (unsigned short*)(ws + 5 * AT);             // [5AT,6AT) — Op dead
    mgemm<4>(XaH, XaL, w1H, w1L, b1, nullptr, 0, nullptr, Hh, Hl,
             Mtok, HIDF, ROI, stream);

    float* Y0 = ws + 3 * AT;                                         // over Xa planes (dead)
    mgemm<2>(Hh, Hl, w2H, w2L, b2, Xa0, ROI, Y0, nullptr, nullptr,
             Mtok, ROI, HIDF, stream);

    float* Xn = ws + 2 * AT;                                         // over Xa0 (dead)
    ln_kernel<<<Mtok, 128, 0, stream>>>(Y0, lng, lnb, Xn);

    float* gfp0 = ws + 3 * AT;                                       // over Y0 (dead)
    colmean_kernel<<<dim3(NB, CTT), 128, 0, stream>>>(Xn, gfp0, N);
    head_kernel<<<NB, 128, 0, stream>>>(gfp0, r1w, r1b, r2w, r2b, probs, N);

    score_kernel<<<dim3(ROI, NB), 128, 0, stream>>>(Mmask, Xn, pws, pwf, pmw, pmb, scores);
    select_kernel<<<NB, 128, 0, stream>>>(scores, idx);
    float* Mp = ws + 4 * AT + 1200000;                               // over Hh (dead)
    gatherm_kernel<<<NB * KPOOL, 128, 0, stream>>>(Mmask, idx, Mp);  // Mmask last use
    float* Xp = ws + 5 * AT;                                         // over Hl (dead)
    unsigned short* XpH = (unsigned short*)(ws + AT);                // over Mmask (dead)
    unsigned short* XpL = XpH + (size_t)NB * KPOOL * ROI;
    gatherx_kernel<<<NB * KPOOL, 128, 0, stream>>>(Xn, scores, idx, Xp, XpH, XpL);
  }

  // ---------------- depth 1: N=280, Mtok=17920
  {
    const int N = KPOOL;
    const int Mtok = NB * N;  // 17920
    const int d = 1;
    const float* wq1 = wq + (size_t)d * ROI * ROI;
    const float* wk1 = wk + (size_t)d * ROI * ROI;
    const float* wv1 = wv + (size_t)d * ROI * ROI;
    const float* wo1 = wo + (size_t)d * ROI * ROI;
    const float* bo1 = bo + (size_t)d * ROI;
    const float* w11 = w1 + (size_t)d * ROI * HIDF;
    const float* b11 = b1 + (size_t)d * HIDF;
    const float* w21 = w2 + (size_t)d * HIDF * ROI;
    const float* b21 = b2 + (size_t)d * ROI;
    const float* lng1 = lng + (size_t)d * ROI;
    const float* lnb1 = lnb + (size_t)d * ROI;
    const float* r1w1 = r1w + (size_t)d * ROI * 128;
    const float* r1b1 = r1b + (size_t)d * 128;
    const float* r2w1 = r2w + (size_t)d * 128 * NC;
    const float* r2b1 = r2b + (size_t)d * NC;

    float* Xp = ws + 5 * AT;
    float* Mp = ws + 4 * AT + 1200000;
    unsigned short* XpH = (unsigned short*)(ws + AT);
    unsigned short* XpL = XpH + (size_t)Mtok * ROI;

    pack_depth(wq1, wk1, wv1, wo1, w11, w21, qkvH, qkvL, woH, woL, w1H, w1L, w2H, w2L, stream);

    unsigned short* QKVH_ = (unsigned short*)(ws + 2 * AT);          // ends before Mp
    unsigned short* QKVL_ = QKVH_ + (size_t)Mtok * (3 * ROI);
    mgemm<6>(XpH, XpL, qkvH, qkvL, nullptr, nullptr, 0, nullptr, QKVH_, QKVL_,
             Mtok, 3 * ROI, ROI, stream);

    unsigned short* OpH = (unsigned short*)(ws + AT);                // over Xp planes (dead)
    unsigned short* OpL = OpH + (size_t)Mtok * ROI;
    fattn_kernel<<<dim3(HEADS * NB, (N + 63) / 64), 256, 0, stream>>>(
        QKVH_, QKVL_, Mp, OpH, OpL, N);

    float* Xa1 = ws + 2 * AT;                                        // over QKV planes (dead)
    unsigned short* XaH = (unsigned short*)(ws + 3 * AT);
    unsigned short* XaL = XaH + (size_t)Mtok * ROI;
    mgemm<5>(OpH, OpL, woH, woL, bo1, Xp, ROI, Xa1, XaH, XaL,
             Mtok, ROI, ROI, stream);

    unsigned short* H1h = (unsigned short*)(ws + 4 * AT);            // Mp dead after fattn
    unsigned short* H1l = (unsigned short*)(ws + 5 * AT);            // Xp dead after Xa1
    mgemm<4>(XaH, XaL, w1H, w1L, b11, nullptr, 0, nullptr, H1h, H1l,
             Mtok, HIDF, ROI, stream);

    float* Y1 = ws + AT;                                             // over Op planes (dead)
    mgemm<2>(H1h, H1l, w2H, w2L, b21, Xa1, ROI, Y1, nullptr, nullptr,
             Mtok, ROI, HIDF, stream);

    float* Xf = ws + 3 * AT;                                         // over Xa planes (dead)
    ln_kernel<<<Mtok, 128, 0, stream>>>(Y1, lng1, lnb1, Xf);

    float* gfp1 = ws + 2 * AT;                                       // over Xa1 (dead)
    colmean_kernel<<<dim3(NB, CTT), 128, 0, stream>>>(Xf, gfp1, N);
    head_kernel<<<NB, 128, 0, stream>>>(gfp1, r1w1, r1b1, r2w1, r2b1, probs + NB * NC, N);
    finalize_kernel<<<NB, 128, 0, stream>>>(gfp1, probs, out, N);
  }
  (void)in_sizes; (void)n_in; (void)out_size; (void)ws_size;
}